// Round 1
// baseline (2598.976 us; speedup 1.0000x reference)
//
#include <hip/hip_runtime.h>

#define NPIX 4096
#define CHN  64

__device__ __forceinline__ float lrelu_(float x){ return x >= 0.f ? x : 0.01f*x; }

// ---------------- positional embedding table [32][4096] ----------------
// Replicates the torch .view bug: t = pe([64,16]).reshape(16,64) is a flat
// reinterpret. pos[c][n] = t[c][n>>6] (c<16) or t[c-16][n&63] (c>=16).
__global__ void pos_kernel(float* __restrict__ pos){
  int idx = blockIdx.x*256 + threadIdx.x;       // 32*4096 = 131072
  int c = idx >> 12;
  int n = idx & (NPIX-1);
  int bcoord = (c < 16) ? (n >> 6) : (n & 63);
  int a = (c < 16) ? c : (c - 16);
  int flat = a*64 + bcoord;                     // index into pe flat [64*16]
  int p = flat >> 4;
  int j = flat & 15;
  float val = 0.f;
  if (p != 0){
    float ex = (float)(j & ~1) * (1.f/16.f);
    float w = powf(10000.f, -ex);
    float ang = (float)p * w;
    val = (j & 1) ? cosf(ang) : sinf(ang);
  }
  pos[idx] = val;
}

// ---------------- masked causal 5x5 conv (input layer) ----------------
// allowed taps: ky=0,1: kx 0..4 ; ky=2: kx 0..1 ; rows 3,4 masked out
__global__ void conv_in_kernel(const float* __restrict__ x, const float* __restrict__ cw,
                               const float* __restrict__ cb, float* __restrict__ out){
  int b = blockIdx.x >> 6;
  int o = blockIdx.x & 63;
  float w[3][12];
  #pragma unroll
  for (int ci=0; ci<3; ++ci){
    const float* wp = cw + (o*3+ci)*25;
    #pragma unroll
    for (int tt=0; tt<10; ++tt) w[ci][tt] = wp[tt];   // ky=0,1 taps
    w[ci][10] = wp[10]; w[ci][11] = wp[11];           // ky=2, kx=0,1
  }
  float bias = cb[o];
  for (int px = threadIdx.x; px < NPIX; px += 256){
    int y = px >> 6, xx = px & 63;
    float acc = bias;
    #pragma unroll
    for (int ci=0; ci<3; ++ci){
      const float* xp = x + ((b*3+ci)<<12);
      #pragma unroll
      for (int ky=0; ky<3; ++ky){
        int yy = y + ky - 2;
        if (yy < 0) continue;
        int nk = (ky==2) ? 2 : 5;
        #pragma unroll
        for (int kx=0; kx<5; ++kx){
          if (kx >= nk) break;
          int xc = xx + kx - 2;
          if (xc < 0 || xc > 63) continue;
          acc += xp[(yy<<6) + xc] * w[ci][ky*5+kx];
        }
      }
    }
    out[(b*CHN+o)*NPIX + px] = acc;
  }
}

// ---------------- batch-norm stats (biased var) per channel ----------------
__global__ void bn_stats_kernel(const float* __restrict__ xin, float* __restrict__ stats){
  int c = blockIdx.x;
  float s = 0.f, ss = 0.f;
  for (int idx = threadIdx.x; idx < 2*NPIX; idx += 256){
    int b = idx >> 12;
    int n = idx & (NPIX-1);
    float v = xin[(b*CHN + c)*NPIX + n];
    s += v; ss += v*v;
  }
  __shared__ float rs[256], rq[256];
  rs[threadIdx.x] = s; rq[threadIdx.x] = ss;
  __syncthreads();
  for (int st=128; st>0; st>>=1){
    if (threadIdx.x < st){ rs[threadIdx.x]+=rs[threadIdx.x+st]; rq[threadIdx.x]+=rq[threadIdx.x+st]; }
    __syncthreads();
  }
  if (threadIdx.x==0){
    float mu = rs[0]*(1.f/8192.f);
    float var = rq[0]*(1.f/8192.f) - mu*mu;
    var = fmaxf(var, 0.f);
    stats[c*2]   = mu;
    stats[c*2+1] = rsqrtf(var + 1e-5f);
  }
}

// ---------------- BN apply + LeakyReLU ----------------
__global__ void bn_apply_kernel(const float* __restrict__ xin, const float* __restrict__ stats,
                                const float* __restrict__ g, const float* __restrict__ bb,
                                float* __restrict__ hout){
  int idx = blockIdx.x*256 + threadIdx.x;   // float4 index, 131072 total
  int e = idx << 2;
  int c = (e >> 12) & 63;
  float mu = stats[c*2], rstd = stats[c*2+1];
  float gain = g[c]*rstd;
  float beta = bb[c] - gain*mu;
  float4 v = *(const float4*)(xin + e);
  float4 r;
  r.x = lrelu_(gain*v.x + beta);
  r.y = lrelu_(gain*v.y + beta);
  r.z = lrelu_(gain*v.z + beta);
  r.w = lrelu_(gain*v.w + beta);
  *(float4*)(hout + e) = r;
}

// ---------------- five 1x1 convs: q, fk, ck, fv, cv -> q, k_new, v_new ---------
// grid 256 = b*128 + tile(32 n); block 256: lane = out-channel o, wave -> n-octet
__global__ void cv1_kernel(
    const float* __restrict__ hbuf, const float* __restrict__ pos,
    const float* __restrict__ kold, const float* __restrict__ vold,
    const float* __restrict__ qw,  const float* __restrict__ qbi,
    const float* __restrict__ fkw, const float* __restrict__ fkb,
    const float* __restrict__ ckw, const float* __restrict__ ckb,
    const float* __restrict__ fvw, const float* __restrict__ fvb,
    const float* __restrict__ cvw, const float* __restrict__ cvb,
    float* __restrict__ qout, float* __restrict__ knew, float* __restrict__ vnew)
{
  int t = threadIdx.x;
  int o  = t & 63;
  int wv = t >> 6;
  int b    = blockIdx.x >> 7;
  int tile = blockIdx.x & 127;
  int n0 = tile*32 + wv*8;

  const float* hb = hbuf + b*CHN*NPIX + n0;
  const float* kb = kold + b*CHN*NPIX + n0;
  const float* vb = vold + b*CHN*NPIX + n0;
  const float* pb = pos + n0;

  auto load8 = [&](const float* p, float* dst){
    float4 a = *(const float4*)p;
    float4 c = *(const float4*)(p+4);
    dst[0]=a.x; dst[1]=a.y; dst[2]=a.z; dst[3]=a.w;
    dst[4]=c.x; dst[5]=c.y; dst[6]=c.z; dst[7]=c.w;
  };

  float x[8];
  long obase = (long)(b*CHN+o)*NPIX + n0;

  // ---- q (96 inputs: h, pos) ----
  {
    float aq[8];
    float bias = qbi[o];
    #pragma unroll
    for (int j=0;j<8;++j) aq[j]=bias;
    for (int i=0;i<64;++i){
      load8(hb + i*NPIX, x);
      float w = qw[o*96+i];
      #pragma unroll
      for (int j=0;j<8;++j) aq[j] += w*x[j];
    }
    for (int i=0;i<32;++i){
      load8(pb + i*NPIX, x);
      float w = qw[o*96+64+i];
      #pragma unroll
      for (int j=0;j<8;++j) aq[j] += w*x[j];
    }
    #pragma unroll
    for (int j=0;j<8;++j) qout[obase+j] = lrelu_(aq[j]);
  }

  // ---- fk/ck (160 inputs: h, pos, k_old) -> k_new ----
  {
    float af[8], ac[8];
    float bf = fkb[o], bc = ckb[o];
    #pragma unroll
    for (int j=0;j<8;++j){ af[j]=bf; ac[j]=bc; }
    for (int i=0;i<64;++i){
      load8(hb + i*NPIX, x);
      float wf = fkw[o*160+i], wc = ckw[o*160+i];
      #pragma unroll
      for (int j=0;j<8;++j){ af[j] += wf*x[j]; ac[j] += wc*x[j]; }
    }
    for (int i=0;i<32;++i){
      load8(pb + i*NPIX, x);
      float wf = fkw[o*160+64+i], wc = ckw[o*160+64+i];
      #pragma unroll
      for (int j=0;j<8;++j){ af[j] += wf*x[j]; ac[j] += wc*x[j]; }
    }
    for (int i=0;i<64;++i){
      load8(kb + i*NPIX, x);
      float wf = fkw[o*160+96+i], wc = ckw[o*160+96+i];
      #pragma unroll
      for (int j=0;j<8;++j){ af[j] += wf*x[j]; ac[j] += wc*x[j]; }
    }
    float kv[8];
    load8(kb + o*NPIX, kv);
    #pragma unroll
    for (int j=0;j<8;++j){
      float fk = 1.f/(1.f+__expf(-af[j]));
      knew[obase+j] = fk*kv[j] + lrelu_(ac[j]);
    }
  }

  // ---- fv/cv (160 inputs: h, pos, v_old) -> v_new ----
  {
    float af[8], ac[8];
    float bf = fvb[o], bc = cvb[o];
    #pragma unroll
    for (int j=0;j<8;++j){ af[j]=bf; ac[j]=bc; }
    for (int i=0;i<64;++i){
      load8(hb + i*NPIX, x);
      float wf = fvw[o*160+i], wc = cvw[o*160+i];
      #pragma unroll
      for (int j=0;j<8;++j){ af[j] += wf*x[j]; ac[j] += wc*x[j]; }
    }
    for (int i=0;i<32;++i){
      load8(pb + i*NPIX, x);
      float wf = fvw[o*160+64+i], wc = cvw[o*160+64+i];
      #pragma unroll
      for (int j=0;j<8;++j){ af[j] += wf*x[j]; ac[j] += wc*x[j]; }
    }
    for (int i=0;i<64;++i){
      load8(vb + i*NPIX, x);
      float wf = fvw[o*160+96+i], wc = cvw[o*160+96+i];
      #pragma unroll
      for (int j=0;j<8;++j){ af[j] += wf*x[j]; ac[j] += wc*x[j]; }
    }
    float vv[8];
    load8(vb + o*NPIX, vv);
    #pragma unroll
    for (int j=0;j<8;++j){
      float fv = 1.f/(1.f+__expf(-af[j]));
      vnew[obase+j] = fv*vv[j] + lrelu_(ac[j]);
    }
  }
}

// ---------------- causal flash attention (fp32) ----------------
// grid 256: b = bid&1, row-tile (32 rows) issued longest-first.
// block 256: row r = t>>3 (8 lanes/row, g = t&7). Online softmax.
// Masked cols produce exp(-1e30-m)=0 exactly == reference's exp(-10000-max) underflow.
__global__ __launch_bounds__(256) void attn_kernel(
    const float* __restrict__ q, const float* __restrict__ kbuf,
    const float* __restrict__ vbuf, float* __restrict__ out1)
{
  int bid = blockIdx.x;
  int b  = bid & 1;
  int rt = 127 - (bid >> 1);     // longest blocks dispatched first
  int t = threadIdx.x;
  int r = t >> 3;
  int g = t & 7;
  int row = rt*32 + r;

  const float* qp = q    + b*CHN*NPIX;
  const float* kp = kbuf + b*CHN*NPIX;
  const float* vp = vbuf + b*CHN*NPIX;

  __shared__ float Kl[64][68];   // [dim][col]
  __shared__ float Vl[64][68];   // transposed: [col][vdim]
  __shared__ float Pl[32][68];   // [row][col]

  float qr[64];
  #pragma unroll
  for (int d=0; d<64; ++d) qr[d] = qp[d*NPIX + row] * 0.125f;  // fold 1/sqrt(64)

  float acc[8];
  #pragma unroll
  for (int j=0;j<8;++j) acc[j]=0.f;
  float m_run = -1e30f, l_run = 0.f;

  int mt_max = (rt*32 + 31) >> 6;
  int dload = t >> 2;
  int c0 = (t & 3) << 4;

  for (int mt = 0; mt <= mt_max; ++mt){
    int m0 = mt << 6;
    // stage K [d][c] and V transposed [c][vd]
    {
      const float* ksrc = kp + dload*NPIX + m0 + c0;
      const float* vsrc = vp + dload*NPIX + m0 + c0;
      float4 k0 = *(const float4*)(ksrc);
      float4 k1 = *(const float4*)(ksrc+4);
      float4 k2 = *(const float4*)(ksrc+8);
      float4 k3 = *(const float4*)(ksrc+12);
      *(float4*)&Kl[dload][c0]    = k0;
      *(float4*)&Kl[dload][c0+4]  = k1;
      *(float4*)&Kl[dload][c0+8]  = k2;
      *(float4*)&Kl[dload][c0+12] = k3;
      float4 v0 = *(const float4*)(vsrc);
      float4 v1 = *(const float4*)(vsrc+4);
      float4 v2 = *(const float4*)(vsrc+8);
      float4 v3 = *(const float4*)(vsrc+12);
      float vvv[16] = {v0.x,v0.y,v0.z,v0.w, v1.x,v1.y,v1.z,v1.w,
                       v2.x,v2.y,v2.z,v2.w, v3.x,v3.y,v3.z,v3.w};
      #pragma unroll
      for (int i=0;i<16;++i) Vl[c0+i][dload] = vvv[i];
    }
    __syncthreads();

    // S = Q . K  (8 cols per lane)
    float s[8];
    #pragma unroll
    for (int ci=0;ci<8;++ci) s[ci]=0.f;
    #pragma unroll
    for (int d=0; d<64; ++d){
      float4 ka  = *(const float4*)&Kl[d][g*8];
      float4 kb2 = *(const float4*)&Kl[d][g*8+4];
      float qd = qr[d];
      s[0]+=qd*ka.x;  s[1]+=qd*ka.y;  s[2]+=qd*ka.z;  s[3]+=qd*ka.w;
      s[4]+=qd*kb2.x; s[5]+=qd*kb2.y; s[6]+=qd*kb2.z; s[7]+=qd*kb2.w;
    }
    float mx = -1e30f;
    int cbase = m0 + g*8;
    #pragma unroll
    for (int ci=0;ci<8;++ci){
      if (cbase + ci > row) s[ci] = -1e30f;
      mx = fmaxf(mx, s[ci]);
    }
    mx = fmaxf(mx, __shfl_xor(mx,1));
    mx = fmaxf(mx, __shfl_xor(mx,2));
    mx = fmaxf(mx, __shfl_xor(mx,4));
    float m_new = fmaxf(m_run, mx);
    float alpha = __expf(m_run - m_new);
    float p[8]; float ps = 0.f;
    #pragma unroll
    for (int ci=0;ci<8;++ci){ p[ci] = __expf(s[ci]-m_new); ps += p[ci]; }
    ps += __shfl_xor(ps,1); ps += __shfl_xor(ps,2); ps += __shfl_xor(ps,4);
    l_run = l_run*alpha + ps;
    m_run = m_new;

    float4 pa = {p[0],p[1],p[2],p[3]}, pb2 = {p[4],p[5],p[6],p[7]};
    *(float4*)&Pl[r][g*8]   = pa;     // written & read within the same wave
    *(float4*)&Pl[r][g*8+4] = pb2;

    #pragma unroll
    for (int j=0;j<8;++j) acc[j] *= alpha;
    #pragma unroll
    for (int c=0;c<64;++c){
      float pv = Pl[r][c];
      float4 va  = *(const float4*)&Vl[c][g*8];
      float4 vb2 = *(const float4*)&Vl[c][g*8+4];
      acc[0]+=pv*va.x;  acc[1]+=pv*va.y;  acc[2]+=pv*va.z;  acc[3]+=pv*va.w;
      acc[4]+=pv*vb2.x; acc[5]+=pv*vb2.y; acc[6]+=pv*vb2.z; acc[7]+=pv*vb2.w;
    }
    __syncthreads();
  }

  float invl = 1.f / l_run;
  long obase = (long)(b*CHN)*NPIX;
  #pragma unroll
  for (int j=0;j<8;++j)
    out1[obase + (long)(g*8+j)*NPIX + row] = acc[j]*invl;
}

// ---------------- final 1x1 conv: [100,64] x h ----------------
__global__ void final_kernel(const float* __restrict__ h, const float* __restrict__ ow,
                             const float* __restrict__ ob, float* __restrict__ out){
  int b = blockIdx.x >> 4;
  int n = (blockIdx.x & 15)*256 + threadIdx.x;
  float hv[64];
  #pragma unroll
  for (int v=0; v<64; ++v) hv[v] = h[(b*CHN+v)*NPIX + n];
  for (int oc=0; oc<100; ++oc){
    float acc = ob[oc];
    #pragma unroll
    for (int v=0; v<64; ++v) acc += ow[oc*64+v]*hv[v];
    out[((long)b*100 + oc)*NPIX + n] = acc;
  }
}

extern "C" void kernel_launch(void* const* d_in, const int* in_sizes, int n_in,
                              void* d_out, int out_size, void* d_ws, size_t ws_size,
                              hipStream_t stream){
  const float* x     = (const float*)d_in[0];
  const float* convw = (const float*)d_in[1];
  const float* convb = (const float*)d_in[2];
  const float* bn0g  = (const float*)d_in[3];
  const float* bn0b  = (const float*)d_in[4];
  const float* qw    = (const float*)d_in[5];
  const float* qbias = (const float*)d_in[6];
  const float* fkw   = (const float*)d_in[7];
  const float* fkb   = (const float*)d_in[8];
  const float* ckw   = (const float*)d_in[9];
  const float* ckb   = (const float*)d_in[10];
  const float* fvw   = (const float*)d_in[11];
  const float* fvb   = (const float*)d_in[12];
  const float* cvw   = (const float*)d_in[13];
  const float* cvb   = (const float*)d_in[14];
  const float* bng   = (const float*)d_in[15];
  const float* bnb   = (const float*)d_in[16];
  const float* ow    = (const float*)d_in[17];
  const float* ob    = (const float*)d_in[18];

  const size_t TEN = (size_t)2*CHN*NPIX;   // 524288 floats
  float* ws   = (float*)d_ws;
  float* pos  = ws;                 // 32*4096
  float* h    = pos + 32*NPIX;
  float* k0   = h  + TEN;
  float* k1   = k0 + TEN;
  float* v0   = k1 + TEN;
  float* v1   = v0 + TEN;
  float* qbuf = v1 + TEN;
  float* o1   = qbuf + TEN;
  float* stats = o1 + TEN;          // 128

  hipMemsetAsync(k0, 0, TEN*sizeof(float), stream);
  hipMemsetAsync(v0, 0, TEN*sizeof(float), stream);

  pos_kernel<<<512,256,0,stream>>>(pos);
  conv_in_kernel<<<128,256,0,stream>>>(x, convw, convb, o1);
  bn_stats_kernel<<<64,256,0,stream>>>(o1, stats);
  bn_apply_kernel<<<512,256,0,stream>>>(o1, stats, bn0g, bn0b, h);

  float* kb[2] = {k0,k1};
  float* vb[2] = {v0,v1};
  for (int l=0; l<8; ++l){
    float* kold = kb[l&1]; float* knew = kb[(l+1)&1];
    float* vold = vb[l&1]; float* vnew = vb[(l+1)&1];
    cv1_kernel<<<256,256,0,stream>>>(h, pos, kold, vold,
        qw  + l*64*96,  qbias + l*64,
        fkw + l*64*160, fkb + l*64,
        ckw + l*64*160, ckb + l*64,
        fvw + l*64*160, fvb + l*64,
        cvw + l*64*160, cvb + l*64,
        qbuf, knew, vnew);
    attn_kernel<<<256,256,0,stream>>>(qbuf, kold, vold, o1);
    bn_stats_kernel<<<64,256,0,stream>>>(o1, stats);
    bn_apply_kernel<<<512,256,0,stream>>>(o1, stats, bng + l*64, bnb + l*64, h);
  }
  final_kernel<<<32,256,0,stream>>>(h, ow, ob, (float*)d_out);
}

// Round 3
// 1176.135 us; speedup vs baseline: 2.2098x; 2.2098x over previous
//
#include <hip/hip_runtime.h>

#define NPIX 4096
#define CHN  64

typedef __attribute__((ext_vector_type(8))) short short8;
typedef __attribute__((ext_vector_type(8))) unsigned short ushort8;
typedef __attribute__((ext_vector_type(4))) float f32x4;

__device__ __forceinline__ float lrelu_(float x){ return x >= 0.f ? x : 0.01f*x; }

__device__ __forceinline__ unsigned short f2bf(float x){
  union { float f; unsigned u; } v; v.f = x;
  unsigned r = v.u + 0x7FFF + ((v.u >> 16) & 1);
  return (unsigned short)(r >> 16);
}
__device__ __forceinline__ float bf2f(unsigned short h){
  union { unsigned u; float f; } v; v.u = ((unsigned)h) << 16;
  return v.f;
}

// ---------------- positional embedding table [32][4096] ----------------
__global__ void pos_kernel(float* __restrict__ pos){
  int idx = blockIdx.x*256 + threadIdx.x;       // 32*4096 = 131072
  int c = idx >> 12;
  int n = idx & (NPIX-1);
  int bcoord = (c < 16) ? (n >> 6) : (n & 63);
  int a = (c < 16) ? c : (c - 16);
  int flat = a*64 + bcoord;                     // index into pe flat [64*16]
  int p = flat >> 4;
  int j = flat & 15;
  float val = 0.f;
  if (p != 0){
    float ex = (float)(j & ~1) * (1.f/16.f);
    float w = powf(10000.f, -ex);
    float ang = (float)p * w;
    val = (j & 1) ? cosf(ang) : sinf(ang);
  }
  pos[idx] = val;
}

// ---------------- weight transpose: [64 o][I] -> [I][64 o] per layer ---------
// wt: q 8*96*64 (49152) | fk 8*160*64 | ck | fv | cv (81920 each)
__global__ void wtr_kernel(const float* __restrict__ qw, const float* __restrict__ fkw,
                           const float* __restrict__ ckw, const float* __restrict__ fvw,
                           const float* __restrict__ cvw, float* __restrict__ wt){
  int idx = blockIdx.x*256 + threadIdx.x;
  if (idx >= 376832) return;
  if (idx < 49152){
    int l = idx / 6144, r = idx % 6144, i = r >> 6, o = r & 63;
    wt[idx] = qw[(l*64 + o)*96 + i];
  } else {
    int e = idx - 49152;
    int mat = e / 81920, r = e % 81920;
    int l = r / 10240, rr = r % 10240, i = rr >> 6, o = rr & 63;
    const float* src = (mat==0) ? fkw : (mat==1) ? ckw : (mat==2) ? fvw : cvw;
    wt[idx] = src[(l*64 + o)*160 + i];
  }
}

// ---------------- masked causal 5x5 conv (input layer) ----------------
__global__ void conv_in_kernel(const float* __restrict__ x, const float* __restrict__ cw,
                               const float* __restrict__ cb, float* __restrict__ out){
  int b = blockIdx.x >> 6;
  int o = blockIdx.x & 63;
  float w[3][12];
  #pragma unroll
  for (int ci=0; ci<3; ++ci){
    const float* wp = cw + (o*3+ci)*25;
    #pragma unroll
    for (int tt=0; tt<10; ++tt) w[ci][tt] = wp[tt];
    w[ci][10] = wp[10]; w[ci][11] = wp[11];
  }
  float bias = cb[o];
  for (int px = threadIdx.x; px < NPIX; px += 256){
    int y = px >> 6, xx = px & 63;
    float acc = bias;
    #pragma unroll
    for (int ci=0; ci<3; ++ci){
      const float* xp = x + ((b*3+ci)<<12);
      #pragma unroll
      for (int ky=0; ky<3; ++ky){
        int yy = y + ky - 2;
        if (yy < 0) continue;
        int nk = (ky==2) ? 2 : 5;
        #pragma unroll
        for (int kx=0; kx<5; ++kx){
          if (kx >= nk) break;
          int xc = xx + kx - 2;
          if (xc < 0 || xc > 63) continue;
          acc += xp[(yy<<6) + xc] * w[ci][ky*5+kx];
        }
      }
    }
    out[(b*CHN+o)*NPIX + px] = acc;
  }
}

// ---------------- batch-norm stats (biased var) per channel ----------------
__global__ __launch_bounds__(1024) void bn_stats_kernel(const float* __restrict__ xin,
                                                        float* __restrict__ stats){
  int c = blockIdx.x;
  int t = threadIdx.x;
  float s = 0.f, ss = 0.f;
  #pragma unroll
  for (int it=0; it<8; ++it){
    int idx = t + it*1024;
    float v = xin[(((idx>>12))*CHN + c)*NPIX + (idx & (NPIX-1))];
    s += v; ss += v*v;
  }
  #pragma unroll
  for (int o=1; o<64; o<<=1){ s += __shfl_xor(s,o); ss += __shfl_xor(ss,o); }
  __shared__ float ps[16], pq[16];
  if ((t & 63) == 0){ ps[t>>6] = s; pq[t>>6] = ss; }
  __syncthreads();
  if (t == 0){
    float S=0.f, Q=0.f;
    #pragma unroll
    for (int i=0;i<16;++i){ S += ps[i]; Q += pq[i]; }
    float mu = S*(1.f/8192.f);
    float var = Q*(1.f/8192.f) - mu*mu;
    var = fmaxf(var, 0.f);
    stats[c*2]   = mu;
    stats[c*2+1] = rsqrtf(var + 1e-5f);
  }
}

// ---------------- BN apply + LeakyReLU ----------------
__global__ void bn_apply_kernel(const float* __restrict__ xin, const float* __restrict__ stats,
                                const float* __restrict__ g, const float* __restrict__ bb,
                                float* __restrict__ hout){
  int idx = blockIdx.x*256 + threadIdx.x;
  int e = idx << 2;
  int c = (e >> 12) & 63;
  float mu = stats[c*2], rstd = stats[c*2+1];
  float gain = g[c]*rstd;
  float beta = bb[c] - gain*mu;
  float4 v = *(const float4*)(xin + e);
  float4 r;
  r.x = lrelu_(gain*v.x + beta);
  r.y = lrelu_(gain*v.y + beta);
  r.z = lrelu_(gain*v.z + beta);
  r.w = lrelu_(gain*v.w + beta);
  *(float4*)(hout + e) = r;
}

// ---------------- five 1x1 convs -> q(hi/lo), k_new(fp32 + hi/lo), v_new(fp32 + hi/lo^T)
__global__ void cv1_kernel(
    const float* __restrict__ hbuf, const float* __restrict__ pos,
    const float* __restrict__ kold, const float* __restrict__ vold,
    const float* __restrict__ qwt,
    const float* __restrict__ fkwt, const float* __restrict__ ckwt,
    const float* __restrict__ fvwt, const float* __restrict__ cvwt,
    const float* __restrict__ qbi,  const float* __restrict__ fkb,
    const float* __restrict__ ckb,  const float* __restrict__ fvb,
    const float* __restrict__ cvb,
    unsigned short* __restrict__ qh, unsigned short* __restrict__ ql,
    float* __restrict__ knew, unsigned short* __restrict__ khn, unsigned short* __restrict__ kln,
    float* __restrict__ vnew, unsigned short* __restrict__ vhTn, unsigned short* __restrict__ vlTn)
{
  int t = threadIdx.x;
  int o  = t & 63;
  int wv = t >> 6;
  int b    = blockIdx.x >> 7;
  int tile = blockIdx.x & 127;
  int n0 = tile*32 + wv*8;

  const float* hb = hbuf + b*CHN*NPIX + n0;
  const float* kb = kold + b*CHN*NPIX + n0;
  const float* vb = vold + b*CHN*NPIX + n0;
  const float* pb = pos + n0;

  auto load8 = [&](const float* p, float* dst){
    float4 a = *(const float4*)p;
    float4 c = *(const float4*)(p+4);
    dst[0]=a.x; dst[1]=a.y; dst[2]=a.z; dst[3]=a.w;
    dst[4]=c.x; dst[5]=c.y; dst[6]=c.z; dst[7]=c.w;
  };

  float x[8];
  long obase = (long)(b*CHN+o)*NPIX + n0;
  size_t nbase = ((size_t)b*NPIX + n0)*64 + o;   // [b][n][64] bf16 layouts

  // ---- q (96 inputs: h, pos) ----
  {
    float aq[8];
    float bias = qbi[o];
    #pragma unroll
    for (int j=0;j<8;++j) aq[j]=bias;
    for (int i=0;i<64;++i){
      load8(hb + i*NPIX, x);
      float w = qwt[i*64 + o];
      #pragma unroll
      for (int j=0;j<8;++j) aq[j] += w*x[j];
    }
    for (int i=0;i<32;++i){
      load8(pb + i*NPIX, x);
      float w = qwt[(64+i)*64 + o];
      #pragma unroll
      for (int j=0;j<8;++j) aq[j] += w*x[j];
    }
    #pragma unroll
    for (int j=0;j<8;++j){
      float v = lrelu_(aq[j]);
      unsigned short hb16 = f2bf(v);
      qh[nbase + (size_t)j*64] = hb16;
      ql[nbase + (size_t)j*64] = f2bf(v - bf2f(hb16));
    }
  }

  // ---- fk/ck -> k_new ----
  {
    float af[8], ac[8];
    float bf = fkb[o], bc = ckb[o];
    #pragma unroll
    for (int j=0;j<8;++j){ af[j]=bf; ac[j]=bc; }
    for (int i=0;i<64;++i){
      load8(hb + i*NPIX, x);
      float wf = fkwt[i*64+o], wc = ckwt[i*64+o];
      #pragma unroll
      for (int j=0;j<8;++j){ af[j] += wf*x[j]; ac[j] += wc*x[j]; }
    }
    for (int i=0;i<32;++i){
      load8(pb + i*NPIX, x);
      float wf = fkwt[(64+i)*64+o], wc = ckwt[(64+i)*64+o];
      #pragma unroll
      for (int j=0;j<8;++j){ af[j] += wf*x[j]; ac[j] += wc*x[j]; }
    }
    for (int i=0;i<64;++i){
      load8(kb + i*NPIX, x);
      float wf = fkwt[(96+i)*64+o], wc = ckwt[(96+i)*64+o];
      #pragma unroll
      for (int j=0;j<8;++j){ af[j] += wf*x[j]; ac[j] += wc*x[j]; }
    }
    float kv[8];
    load8(kb + o*NPIX, kv);
    #pragma unroll
    for (int j=0;j<8;++j){
      float fk = 1.f/(1.f+__expf(-af[j]));
      float kn = fk*kv[j] + lrelu_(ac[j]);
      knew[obase+j] = kn;
      unsigned short hb16 = f2bf(kn);
      khn[nbase + (size_t)j*64] = hb16;
      kln[nbase + (size_t)j*64] = f2bf(kn - bf2f(hb16));
    }
  }

  // ---- fv/cv -> v_new ----
  {
    float af[8], ac[8];
    float bf = fvb[o], bc = cvb[o];
    #pragma unroll
    for (int j=0;j<8;++j){ af[j]=bf; ac[j]=bc; }
    for (int i=0;i<64;++i){
      load8(hb + i*NPIX, x);
      float wf = fvwt[i*64+o], wc = cvwt[i*64+o];
      #pragma unroll
      for (int j=0;j<8;++j){ af[j] += wf*x[j]; ac[j] += wc*x[j]; }
    }
    for (int i=0;i<32;++i){
      load8(pb + i*NPIX, x);
      float wf = fvwt[(64+i)*64+o], wc = cvwt[(64+i)*64+o];
      #pragma unroll
      for (int j=0;j<8;++j){ af[j] += wf*x[j]; ac[j] += wc*x[j]; }
    }
    for (int i=0;i<64;++i){
      load8(vb + i*NPIX, x);
      float wf = fvwt[(96+i)*64+o], wc = cvwt[(96+i)*64+o];
      #pragma unroll
      for (int j=0;j<8;++j){ af[j] += wf*x[j]; ac[j] += wc*x[j]; }
    }
    float vv[8];
    load8(vb + o*NPIX, vv);
    ushort8 vph, vpl;
    #pragma unroll
    for (int j=0;j<8;++j){
      float fv = 1.f/(1.f+__expf(-af[j]));
      float vn = fv*vv[j] + lrelu_(ac[j]);
      vnew[obase+j] = vn;
      unsigned short hb16 = f2bf(vn);
      vph[j] = hb16;
      vpl[j] = f2bf(vn - bf2f(hb16));
    }
    *(ushort8*)(vhTn + ((size_t)(b*CHN+o))*NPIX + n0) = vph;   // [vd][n]
    *(ushort8*)(vlTn + ((size_t)(b*CHN+o))*NPIX + n0) = vpl;
  }
}

// ---------------- MFMA flash attention, phase 1 (bf16 hi/lo split, fp32-accurate) ----
// grid 640: b(2) x band decomposition (rt 0..127 [32 rows], chunks of 1024 cols).
// block 128 = 2 waves x 16 q-rows. Swapped MFMA: S^T = K.Q^T, out^T = V^T.P^T.
// Each product done as 3 MFMAs: Ah*Bh + Al*Bh + Ah*Bl  (lo*lo ~ 2^-16, dropped).
__global__ __launch_bounds__(128) void attn_mfma(
    const unsigned short* __restrict__ qhg, const unsigned short* __restrict__ qlg,
    const unsigned short* __restrict__ khg, const unsigned short* __restrict__ klg,
    const unsigned short* __restrict__ vhg, const unsigned short* __restrict__ vlg,
    float* __restrict__ part)
{
  int bid = 639 - (int)blockIdx.x;           // longest bands dispatched first
  int b = 0, id = bid;
  if (id >= 320){ b = 1; id -= 320; }
  int pidx = bid;
  int rem = id, k = 0;
  while (rem >= 32*(k+1)){ rem -= 32*(k+1); ++k; }
  int rt    = 32*k + rem/(k+1);
  int chunk = rem - (rem/(k+1))*(k+1);

  int C0  = chunk << 10;                      // 1024*chunk
  int end = min(C0 + 1024, rt*32 + 32);
  int nt  = (end - C0 + 63) >> 6;

  int t = threadIdx.x;
  int w = t >> 6;
  int l = t & 63;
  int r = l & 15;
  int g = l >> 4;
  int n_g = rt*32 + w*16 + r;                 // this lane's q-row

  __shared__ __align__(16) char KH[8192], KL[8192];  // [64 m][64 d] bf16, chunk-XOR swizzle
  __shared__ __align__(16) char VH[8192], VL[8192];  // [64 vd][64 m] bf16, swizzled
  __shared__ __align__(16) char PH[2][2048], PL[2][2048]; // per-wave [16 n][64 m]

  const unsigned short* qhp = qhg + (size_t)b*NPIX*64;
  const unsigned short* qlp = qlg + (size_t)b*NPIX*64;
  const unsigned short* khp = khg + (size_t)b*NPIX*64;
  const unsigned short* klp = klg + (size_t)b*NPIX*64;
  const unsigned short* vhp = vhg + (size_t)b*CHN*NPIX;
  const unsigned short* vlp = vlg + (size_t)b*CHN*NPIX;

  short8 qh0 = *(const short8*)(qhp + (size_t)n_g*64 + 8*g);
  short8 qh1 = *(const short8*)(qhp + (size_t)n_g*64 + 8*g + 32);
  short8 ql0 = *(const short8*)(qlp + (size_t)n_g*64 + 8*g);
  short8 ql1 = *(const short8*)(qlp + (size_t)n_g*64 + 8*g + 32);

  f32x4 zero4 = {0.f,0.f,0.f,0.f};
  f32x4 oacc[4];
  #pragma unroll
  for (int vf=0; vf<4; ++vf) oacc[vf] = zero4;
  float m_run = -1e30f, l_run = 0.f;

  int nmax_w = rt*32 + w*16 + 15;

  for (int ti=0; ti<nt; ++ti){
    int m0 = C0 + (ti<<6);
    __syncthreads();
    #pragma unroll
    for (int p=0; p<4; ++p){
      int slot = t + (p<<7);                  // 512 slots / 128 threads
      int row = slot >> 3, cc = slot & 7;
      int off = row*128 + ((cc ^ (row & 7)) << 4);
      *(ushort8*)(KH + off) = *(const ushort8*)(khp + (size_t)(m0+row)*64 + cc*8);
      *(ushort8*)(KL + off) = *(const ushort8*)(klp + (size_t)(m0+row)*64 + cc*8);
      *(ushort8*)(VH + off) = *(const ushort8*)(vhp + (size_t)row*NPIX + m0 + cc*8);
      *(ushort8*)(VL + off) = *(const ushort8*)(vlp + (size_t)row*NPIX + m0 + cc*8);
    }
    __syncthreads();

    if (m0 <= nmax_w){
      // ---- S^T = K . Q^T ----
      f32x4 sf[4];
      #pragma unroll
      for (int mf=0; mf<4; ++mf) sf[mf] = zero4;
      #pragma unroll
      for (int kc=0; kc<2; ++kc){
        short8 qfh = kc ? qh1 : qh0;
        short8 qfl = kc ? ql1 : ql0;
        int ch = ((g + 4*kc) ^ (r & 7)) << 4;
        #pragma unroll
        for (int mf=0; mf<4; ++mf){
          int ro = (16*mf + r)*128;
          short8 ah = *(const short8*)(KH + ro + ch);
          short8 al = *(const short8*)(KL + ro + ch);
          sf[mf] = __builtin_amdgcn_mfma_f32_16x16x32_bf16(ah, qfh, sf[mf], 0,0,0);
          sf[mf] = __builtin_amdgcn_mfma_f32_16x16x32_bf16(al, qfh, sf[mf], 0,0,0);
          sf[mf] = __builtin_amdgcn_mfma_f32_16x16x32_bf16(ah, qfl, sf[mf], 0,0,0);
        }
      }
      // ---- online softmax: lane owns row n_g; scale 1/8 folded here ----
      float pv[16];
      float mx = -1e30f;
      #pragma unroll
      for (int mf=0; mf<4; ++mf){
        #pragma unroll
        for (int q2=0; q2<4; ++q2){
          int mg = m0 + 16*mf + 4*g + q2;
          float s = sf[mf][q2] * 0.125f;
          s = (mg <= n_g) ? s : -1e30f;
          pv[mf*4+q2] = s;
          mx = fmaxf(mx, s);
        }
      }
      mx = fmaxf(mx, __shfl_xor(mx, 16));
      mx = fmaxf(mx, __shfl_xor(mx, 32));
      float m_new = fmaxf(m_run, mx);
      float alpha = __expf(m_run - m_new);
      float ps = 0.f;
      #pragma unroll
      for (int i=0; i<16; ++i){ pv[i] = __expf(pv[i] - m_new); ps += pv[i]; }
      ps += __shfl_xor(ps, 16);
      ps += __shfl_xor(ps, 32);
      l_run = l_run*alpha + ps;
      m_run = m_new;

      // ---- pack P hi/lo -> per-wave LDS tiles (same-wave, in-order DS) ----
      #pragma unroll
      for (int mf=0; mf<4; ++mf){
        unsigned short h_[4], l_[4];
        #pragma unroll
        for (int q2=0; q2<4; ++q2){
          float xv = pv[mf*4+q2];
          h_[q2] = f2bf(xv);
          l_[q2] = f2bf(xv - bf2f(h_[q2]));
        }
        int addr = r*128 + ((((g>>1) + 2*mf) ^ (r & 7)) << 4) + ((g&1)<<3);
        uint2 wh = make_uint2((unsigned)h_[0] | ((unsigned)h_[1]<<16),
                              (unsigned)h_[2] | ((unsigned)h_[3]<<16));
        uint2 wl = make_uint2((unsigned)l_[0] | ((unsigned)l_[1]<<16),
                              (unsigned)l_[2] | ((unsigned)l_[3]<<16));
        *(uint2*)(PH[w] + addr) = wh;
        *(uint2*)(PL[w] + addr) = wl;
      }
      #pragma unroll
      for (int vf=0; vf<4; ++vf) oacc[vf] *= alpha;

      // ---- out^T += V^T . P^T ----
      #pragma unroll
      for (int kc=0; kc<2; ++kc){
        int ch = ((g + 4*kc) ^ (r & 7)) << 4;
        short8 pfh = *(const short8*)(PH[w] + r*128 + ch);
        short8 pfl = *(const short8*)(PL[w] + r*128 + ch);
        #pragma unroll
        for (int vf=0; vf<4; ++vf){
          int ro = (16*vf + r)*128;
          short8 ah = *(const short8*)(VH + ro + ch);
          short8 al = *(const short8*)(VL + ro + ch);
          oacc[vf] = __builtin_amdgcn_mfma_f32_16x16x32_bf16(ah, pfh, oacc[vf], 0,0,0);
          oacc[vf] = __builtin_amdgcn_mfma_f32_16x16x32_bf16(al, pfh, oacc[vf], 0,0,0);
          oacc[vf] = __builtin_amdgcn_mfma_f32_16x16x32_bf16(ah, pfl, oacc[vf], 0,0,0);
        }
      }
    }
  }

  // ---- write partials: acc [32 n][64 vd], then m,l [32 n][2] ----
  float* pacc = part + (size_t)pidx * 2112;
  int nl = w*16 + r;
  #pragma unroll
  for (int vf=0; vf<4; ++vf)
    *(f32x4*)(pacc + nl*64 + 16*vf + 4*g) = oacc[vf];
  if (g == 0){
    pacc[2048 + nl*2]   = m_run;
    pacc[2048 + nl*2+1] = l_run;
  }
}

// ---------------- attention phase 2: combine chunk partials ----------------
__global__ __launch_bounds__(256) void attn_combine(const float* __restrict__ part,
                                                    float* __restrict__ out1){
  int bid = blockIdx.x;               // b*128 + rt
  int b = bid >> 7, rt = bid & 127;
  int k = rt >> 5;
  int nch = k + 1;
  int base = b*320 + 16*k*(k+1) + (rt - 32*k)*nch;

  int t = threadIdx.x;
  int nl = t & 31, vq = t >> 5;       // 32 rows x 8 vd-octets

  float M = -1e30f;
  #pragma unroll
  for (int c=0; c<4; ++c)
    if (c < nch) M = fmaxf(M, part[(size_t)(base+c)*2112 + 2048 + nl*2]);

  float L = 0.f;
  float val[8];
  #pragma unroll
  for (int jj=0; jj<8; ++jj) val[jj] = 0.f;
  #pragma unroll
  for (int c=0; c<4; ++c){
    if (c < nch){
      const float* pa = part + (size_t)(base+c)*2112;
      float wgt = __expf(pa[2048 + nl*2] - M);
      L += pa[2048 + nl*2 + 1] * wgt;
      #pragma unroll
      for (int jj=0; jj<8; ++jj) val[jj] += wgt * pa[nl*64 + vq*8 + jj];
    }
  }
  float invL = 1.f / L;
  #pragma unroll
  for (int jj=0; jj<8; ++jj)
    out1[((size_t)b*CHN + vq*8 + jj)*NPIX + rt*32 + nl] = val[jj]*invL;
}

// ---------------- final 1x1 conv: [100,64] x h ----------------
__global__ void final_kernel(const float* __restrict__ h, const float* __restrict__ ow,
                             const float* __restrict__ ob, float* __restrict__ out){
  int b = blockIdx.x >> 4;
  int n = (blockIdx.x & 15)*256 + threadIdx.x;
  float hv[64];
  #pragma unroll
  for (int v=0; v<64; ++v) hv[v] = h[(b*CHN+v)*NPIX + n];
  for (int oc=0; oc<100; ++oc){
    float acc = ob[oc];
    #pragma unroll
    for (int v=0; v<64; ++v) acc += ow[oc*64+v]*hv[v];
    out[((long)b*100 + oc)*NPIX + n] = acc;
  }
}

extern "C" void kernel_launch(void* const* d_in, const int* in_sizes, int n_in,
                              void* d_out, int out_size, void* d_ws, size_t ws_size,
                              hipStream_t stream){
  const float* x     = (const float*)d_in[0];
  const float* convw = (const float*)d_in[1];
  const float* convb = (const float*)d_in[2];
  const float* bn0g  = (const float*)d_in[3];
  const float* bn0b  = (const float*)d_in[4];
  const float* qw    = (const float*)d_in[5];
  const float* qbias = (const float*)d_in[6];
  const float* fkw   = (const float*)d_in[7];
  const float* fkb   = (const float*)d_in[8];
  const float* ckw   = (const float*)d_in[9];
  const float* ckb   = (const float*)d_in[10];
  const float* fvw   = (const float*)d_in[11];
  const float* fvb   = (const float*)d_in[12];
  const float* cvw   = (const float*)d_in[13];
  const float* cvb   = (const float*)d_in[14];
  const float* bng   = (const float*)d_in[15];
  const float* bnb   = (const float*)d_in[16];
  const float* ow    = (const float*)d_in[17];
  const float* ob    = (const float*)d_in[18];

  const size_t TEN = (size_t)2*CHN*NPIX;   // 524288 elements
  const size_t BFU = TEN/2;                // float-units per bf16 tensor
  float* ws   = (float*)d_ws;
  float* pos  = ws;                 // 131072
  float* h    = pos + 32*NPIX;
  float* k0   = h  + TEN;
  float* k1   = k0 + TEN;
  float* v0   = k1 + TEN;
  float* v1   = v0 + TEN;
  float* o1   = v1 + TEN;
  float* stats = o1 + TEN;          // 128
  float* wt   = stats + 128;        // 376832
  float* bfb  = wt + 376832;
  unsigned short* qh  = (unsigned short*)(bfb);
  unsigned short* ql  = (unsigned short*)(bfb + BFU);
  unsigned short* kh0 = (unsigned short*)(bfb + 2*BFU);
  unsigned short* kh1 = (unsigned short*)(bfb + 3*BFU);
  unsigned short* kl0 = (unsigned short*)(bfb + 4*BFU);
  unsigned short* kl1 = (unsigned short*)(bfb + 5*BFU);
  unsigned short* vh0 = (unsigned short*)(bfb + 6*BFU);
  unsigned short* vh1 = (unsigned short*)(bfb + 7*BFU);
  unsigned short* vl0 = (unsigned short*)(bfb + 8*BFU);
  unsigned short* vl1 = (unsigned short*)(bfb + 9*BFU);
  float* part = bfb + 10*BFU;       // 640 * 2112 floats

  hipMemsetAsync(k0, 0, TEN*sizeof(float), stream);
  hipMemsetAsync(v0, 0, TEN*sizeof(float), stream);
  hipMemsetAsync(kh0, 0, TEN*2, stream);
  hipMemsetAsync(kl0, 0, TEN*2, stream);
  hipMemsetAsync(vh0, 0, TEN*2, stream);
  hipMemsetAsync(vl0, 0, TEN*2, stream);

  pos_kernel<<<512,256,0,stream>>>(pos);
  wtr_kernel<<<1472,256,0,stream>>>(qw, fkw, ckw, fvw, cvw, wt);
  conv_in_kernel<<<128,256,0,stream>>>(x, convw, convb, o1);
  bn_stats_kernel<<<64,1024,0,stream>>>(o1, stats);
  bn_apply_kernel<<<512,256,0,stream>>>(o1, stats, bn0g, bn0b, h);

  float* kfp[2] = {k0,k1};
  float* vfp[2] = {v0,v1};
  unsigned short* khb[2] = {kh0,kh1};
  unsigned short* klb[2] = {kl0,kl1};
  unsigned short* vhb[2] = {vh0,vh1};
  unsigned short* vlb[2] = {vl0,vl1};
  for (int l=0; l<8; ++l){
    float* kold = kfp[l&1]; float* knew = kfp[(l+1)&1];
    float* vold = vfp[l&1]; float* vnew = vfp[(l+1)&1];
    cv1_kernel<<<256,256,0,stream>>>(h, pos, kold, vold,
        wt + l*6144,
        wt + 49152 + l*10240,
        wt + 49152 + 81920 + l*10240,
        wt + 49152 + 2*81920 + l*10240,
        wt + 49152 + 3*81920 + l*10240,
        qbias + l*64, fkb + l*64, ckb + l*64, fvb + l*64, cvb + l*64,
        qh, ql,
        knew, khb[(l+1)&1], klb[(l+1)&1],
        vnew, vhb[(l+1)&1], vlb[(l+1)&1]);
    attn_mfma<<<640,128,0,stream>>>(qh, ql, khb[l&1], klb[l&1], vhb[l&1], vlb[l&1], part);
    attn_combine<<<256,256,0,stream>>>(part, o1);
    bn_stats_kernel<<<64,1024,0,stream>>>(o1, stats);
    bn_apply_kernel<<<512,256,0,stream>>>(o1, stats, bng + l*64, bnb + l*64, h);
  }
  final_kernel<<<32,256,0,stream>>>(h, ow, ob, (float*)d_out);
}

// Round 5
// 869.171 us; speedup vs baseline: 2.9902x; 1.3532x over previous
//
#include <hip/hip_runtime.h>

#define NPIX 4096
#define CHN  64

typedef __attribute__((ext_vector_type(8))) short short8;
typedef __attribute__((ext_vector_type(8))) unsigned short ushort8;
typedef __attribute__((ext_vector_type(4))) unsigned short ushort4v;
typedef __attribute__((ext_vector_type(4))) float f32x4;

__device__ __forceinline__ float lrelu_(float x){ return x >= 0.f ? x : 0.01f*x; }

__device__ __forceinline__ unsigned short f2bf(float x){
  union { float f; unsigned u; } v; v.f = x;
  unsigned r = v.u + 0x7FFF + ((v.u >> 16) & 1);
  return (unsigned short)(r >> 16);
}
__device__ __forceinline__ float bf2f(unsigned short h){
  union { unsigned u; float f; } v; v.u = ((unsigned)h) << 16;
  return v.f;
}

// ---------------- positional embedding table [32][4096] ----------------
__global__ void pos_kernel(float* __restrict__ pos){
  int idx = blockIdx.x*256 + threadIdx.x;       // 32*4096 = 131072
  int c = idx >> 12;
  int n = idx & (NPIX-1);
  int bcoord = (c < 16) ? (n >> 6) : (n & 63);
  int a = (c < 16) ? c : (c - 16);
  int flat = a*64 + bcoord;                     // index into pe flat [64*16]
  int p = flat >> 4;
  int j = flat & 15;
  float val = 0.f;
  if (p != 0){
    float ex = (float)(j & ~1) * (1.f/16.f);
    float w = powf(10000.f, -ex);
    float ang = (float)p * w;
    val = (j & 1) ? cosf(ang) : sinf(ang);
  }
  pos[idx] = val;
}

// ---------------- weight transpose: [64 o][I] -> [I][64 o] per layer ---------
// wt: q 8*96*64 (49152) | fk 8*160*64 | ck | fv | cv (81920 each)
__global__ void wtr_kernel(const float* __restrict__ qw, const float* __restrict__ fkw,
                           const float* __restrict__ ckw, const float* __restrict__ fvw,
                           const float* __restrict__ cvw, float* __restrict__ wt){
  int idx = blockIdx.x*256 + threadIdx.x;
  if (idx >= 376832) return;
  if (idx < 49152){
    int l = idx / 6144, r = idx % 6144, i = r >> 6, o = r & 63;
    wt[idx] = qw[(l*64 + o)*96 + i];
  } else {
    int e = idx - 49152;
    int mat = e / 81920, r = e % 81920;
    int l = r / 10240, rr = r % 10240, i = rr >> 6, o = rr & 63;
    const float* src = (mat==0) ? fkw : (mat==1) ? ckw : (mat==2) ? fvw : cvw;
    wt[idx] = src[(l*64 + o)*160 + i];
  }
}

// ---------------- masked causal 5x5 conv (input layer) ----------------
__global__ void conv_in_kernel(const float* __restrict__ x, const float* __restrict__ cw,
                               const float* __restrict__ cb, float* __restrict__ out){
  int b = blockIdx.x >> 6;
  int o = blockIdx.x & 63;
  float w[3][12];
  #pragma unroll
  for (int ci=0; ci<3; ++ci){
    const float* wp = cw + (o*3+ci)*25;
    #pragma unroll
    for (int tt=0; tt<10; ++tt) w[ci][tt] = wp[tt];
    w[ci][10] = wp[10]; w[ci][11] = wp[11];
  }
  float bias = cb[o];
  for (int px = threadIdx.x; px < NPIX; px += 256){
    int y = px >> 6, xx = px & 63;
    float acc = bias;
    #pragma unroll
    for (int ci=0; ci<3; ++ci){
      const float* xp = x + ((b*3+ci)<<12);
      #pragma unroll
      for (int ky=0; ky<3; ++ky){
        int yy = y + ky - 2;
        if (yy < 0) continue;
        int nk = (ky==2) ? 2 : 5;
        #pragma unroll
        for (int kx=0; kx<5; ++kx){
          if (kx >= nk) break;
          int xc = xx + kx - 2;
          if (xc < 0 || xc > 63) continue;
          acc += xp[(yy<<6) + xc] * w[ci][ky*5+kx];
        }
      }
    }
    out[(b*CHN+o)*NPIX + px] = acc;
  }
}

// ---------------- batch-norm stats (biased var) per channel ----------------
__global__ __launch_bounds__(1024) void bn_stats_kernel(const float* __restrict__ xin,
                                                        float* __restrict__ stats){
  int c = blockIdx.x;
  int t = threadIdx.x;
  float s = 0.f, ss = 0.f;
  #pragma unroll
  for (int it=0; it<8; ++it){
    int idx = t + it*1024;
    float v = xin[(((idx>>12))*CHN + c)*NPIX + (idx & (NPIX-1))];
    s += v; ss += v*v;
  }
  #pragma unroll
  for (int o=1; o<64; o<<=1){ s += __shfl_xor(s,o); ss += __shfl_xor(ss,o); }
  __shared__ float ps[16], pq[16];
  if ((t & 63) == 0){ ps[t>>6] = s; pq[t>>6] = ss; }
  __syncthreads();
  if (t == 0){
    float S=0.f, Q=0.f;
    #pragma unroll
    for (int i=0;i<16;++i){ S += ps[i]; Q += pq[i]; }
    float mu = S*(1.f/8192.f);
    float var = Q*(1.f/8192.f) - mu*mu;
    var = fmaxf(var, 0.f);
    stats[c*2]   = mu;
    stats[c*2+1] = rsqrtf(var + 1e-5f);
  }
}

// ---------------- BN apply + LeakyReLU ----------------
__global__ void bn_apply_kernel(const float* __restrict__ xin, const float* __restrict__ stats,
                                const float* __restrict__ g, const float* __restrict__ bb,
                                float* __restrict__ hout){
  int idx = blockIdx.x*256 + threadIdx.x;
  int e = idx << 2;
  int c = (e >> 12) & 63;
  float mu = stats[c*2], rstd = stats[c*2+1];
  float gain = g[c]*rstd;
  float beta = bb[c] - gain*mu;
  float4 v = *(const float4*)(xin + e);
  float4 r;
  r.x = lrelu_(gain*v.x + beta);
  r.y = lrelu_(gain*v.y + beta);
  r.z = lrelu_(gain*v.z + beta);
  r.w = lrelu_(gain*v.w + beta);
  *(float4*)(hout + e) = r;
}

// ---------------- five 1x1 convs -> q(hi/lo), k_new(fp32 + hi/lo), v_new(fp32 + hi/lo^T)
// grid 512 = b*256 + tile(16 n); block 256 = 4 waves x 4 px; lane = out-channel o
__global__ __launch_bounds__(256) void cv1_kernel(
    const float* __restrict__ hbuf, const float* __restrict__ pos,
    const float* __restrict__ kold, const float* __restrict__ vold,
    const float* __restrict__ qwt,
    const float* __restrict__ fkwt, const float* __restrict__ ckwt,
    const float* __restrict__ fvwt, const float* __restrict__ cvwt,
    const float* __restrict__ qbi,  const float* __restrict__ fkb,
    const float* __restrict__ ckb,  const float* __restrict__ fvb,
    const float* __restrict__ cvb,
    unsigned short* __restrict__ qh, unsigned short* __restrict__ ql,
    float* __restrict__ knew, unsigned short* __restrict__ khn, unsigned short* __restrict__ kln,
    float* __restrict__ vnew, unsigned short* __restrict__ vhTn, unsigned short* __restrict__ vlTn)
{
  int t = threadIdx.x;
  int o  = t & 63;
  int wv = t >> 6;                      // 0..3
  int b    = blockIdx.x >> 8;           // grid 512: 0..511
  int tile = blockIdx.x & 255;          // 256 tiles x 16 px = 4096
  int n0 = tile*16 + wv*4;

  const float* hb = hbuf + b*CHN*NPIX + n0;
  const float* kb = kold + b*CHN*NPIX + n0;
  const float* vb = vold + b*CHN*NPIX + n0;
  const float* pb = pos + n0;

  auto load4 = [&](const float* p, float* dst){
    float4 a = *(const float4*)p;
    dst[0]=a.x; dst[1]=a.y; dst[2]=a.z; dst[3]=a.w;
  };

  float x[4];
  long obase = (long)(b*CHN+o)*NPIX + n0;
  size_t nbase = ((size_t)b*NPIX + n0)*64 + o;   // [b][n][64] bf16 layouts

  // ---- q (96 inputs: h, pos); 1/8 attention scale folded in ----
  {
    float aq[4];
    float bias = qbi[o];
    #pragma unroll
    for (int j=0;j<4;++j) aq[j]=bias;
    #pragma unroll 4
    for (int i=0;i<64;++i){
      load4(hb + i*NPIX, x);
      float w = qwt[i*64 + o];
      #pragma unroll
      for (int j=0;j<4;++j) aq[j] += w*x[j];
    }
    #pragma unroll 4
    for (int i=0;i<32;++i){
      load4(pb + i*NPIX, x);
      float w = qwt[(64+i)*64 + o];
      #pragma unroll
      for (int j=0;j<4;++j) aq[j] += w*x[j];
    }
    #pragma unroll
    for (int j=0;j<4;++j){
      float v = lrelu_(aq[j]) * 0.125f;
      unsigned short hb16 = f2bf(v);
      qh[nbase + (size_t)j*64] = hb16;
      ql[nbase + (size_t)j*64] = f2bf(v - bf2f(hb16));
    }
  }

  // ---- fk/ck -> k_new ----
  {
    float af[4], ac[4];
    float bf = fkb[o], bc = ckb[o];
    #pragma unroll
    for (int j=0;j<4;++j){ af[j]=bf; ac[j]=bc; }
    #pragma unroll 4
    for (int i=0;i<64;++i){
      load4(hb + i*NPIX, x);
      float wf = fkwt[i*64+o], wc = ckwt[i*64+o];
      #pragma unroll
      for (int j=0;j<4;++j){ af[j] += wf*x[j]; ac[j] += wc*x[j]; }
    }
    #pragma unroll 4
    for (int i=0;i<32;++i){
      load4(pb + i*NPIX, x);
      float wf = fkwt[(64+i)*64+o], wc = ckwt[(64+i)*64+o];
      #pragma unroll
      for (int j=0;j<4;++j){ af[j] += wf*x[j]; ac[j] += wc*x[j]; }
    }
    #pragma unroll 4
    for (int i=0;i<64;++i){
      load4(kb + i*NPIX, x);
      float wf = fkwt[(96+i)*64+o], wc = ckwt[(96+i)*64+o];
      #pragma unroll
      for (int j=0;j<4;++j){ af[j] += wf*x[j]; ac[j] += wc*x[j]; }
    }
    float kv[4];
    load4(kb + o*NPIX, kv);
    #pragma unroll
    for (int j=0;j<4;++j){
      float fk = 1.f/(1.f+__expf(-af[j]));
      float kn = fk*kv[j] + lrelu_(ac[j]);
      knew[obase+j] = kn;
      unsigned short hb16 = f2bf(kn);
      khn[nbase + (size_t)j*64] = hb16;
      kln[nbase + (size_t)j*64] = f2bf(kn - bf2f(hb16));
    }
  }

  // ---- fv/cv -> v_new ----
  {
    float af[4], ac[4];
    float bf = fvb[o], bc = cvb[o];
    #pragma unroll
    for (int j=0;j<4;++j){ af[j]=bf; ac[j]=bc; }
    #pragma unroll 4
    for (int i=0;i<64;++i){
      load4(hb + i*NPIX, x);
      float wf = fvwt[i*64+o], wc = cvwt[i*64+o];
      #pragma unroll
      for (int j=0;j<4;++j){ af[j] += wf*x[j]; ac[j] += wc*x[j]; }
    }
    #pragma unroll 4
    for (int i=0;i<32;++i){
      load4(pb + i*NPIX, x);
      float wf = fvwt[(64+i)*64+o], wc = cvwt[(64+i)*64+o];
      #pragma unroll
      for (int j=0;j<4;++j){ af[j] += wf*x[j]; ac[j] += wc*x[j]; }
    }
    #pragma unroll 4
    for (int i=0;i<64;++i){
      load4(vb + i*NPIX, x);
      float wf = fvwt[(96+i)*64+o], wc = cvwt[(96+i)*64+o];
      #pragma unroll
      for (int j=0;j<4;++j){ af[j] += wf*x[j]; ac[j] += wc*x[j]; }
    }
    float vv[4];
    load4(vb + o*NPIX, vv);
    ushort4v vph, vpl;
    #pragma unroll
    for (int j=0;j<4;++j){
      float fv = 1.f/(1.f+__expf(-af[j]));
      float vn = fv*vv[j] + lrelu_(ac[j]);
      vnew[obase+j] = vn;
      unsigned short hb16 = f2bf(vn);
      vph[j] = hb16;
      vpl[j] = f2bf(vn - bf2f(hb16));
    }
    *(ushort4v*)(vhTn + ((size_t)(b*CHN+o))*NPIX + n0) = vph;   // [vd][n]
    *(ushort4v*)(vlTn + ((size_t)(b*CHN+o))*NPIX + n0) = vpl;
  }
}

// ---------------- MFMA flash attention, phase 1 (bf16 hi/lo split, fp32-accurate) ----
// grid 640: b(2) x band decomposition (rt 0..127 [32 rows], chunks of 1024 cols).
// block 128 = 2 waves x 16 q-rows. Swapped MFMA: S^T = K.Q^T, out^T = V^T.P^T.
// Each product done as 3 MFMAs: Ah*Bh + Al*Bh + Ah*Bl  (lo*lo ~ 2^-16, dropped).
__global__ __launch_bounds__(128) void attn_mfma(
    const unsigned short* __restrict__ qhg, const unsigned short* __restrict__ qlg,
    const unsigned short* __restrict__ khg, const unsigned short* __restrict__ klg,
    const unsigned short* __restrict__ vhg, const unsigned short* __restrict__ vlg,
    float* __restrict__ part)
{
  int bid = 639 - (int)blockIdx.x;           // longest bands dispatched first
  int b = 0, id = bid;
  if (id >= 320){ b = 1; id -= 320; }
  int pidx = bid;
  int rem = id, k = 0;
  while (rem >= 32*(k+1)){ rem -= 32*(k+1); ++k; }
  int rt    = 32*k + rem/(k+1);
  int chunk = rem - (rem/(k+1))*(k+1);

  int C0  = chunk << 10;                      // 1024*chunk
  int end = min(C0 + 1024, rt*32 + 32);
  int nt  = (end - C0 + 63) >> 6;

  int t = threadIdx.x;
  int w = t >> 6;
  int l = t & 63;
  int r = l & 15;
  int g = l >> 4;
  int n_g = rt*32 + w*16 + r;                 // this lane's q-row

  __shared__ __align__(16) char KH[8192], KL[8192];  // [64 m][64 d] bf16, chunk-XOR swizzle
  __shared__ __align__(16) char VH[8192], VL[8192];  // [64 vd][64 m] bf16, swizzled
  __shared__ __align__(16) char PH[2][2048], PL[2][2048]; // per-wave [16 n][64 m]

  const unsigned short* qhp = qhg + (size_t)b*NPIX*64;
  const unsigned short* qlp = qlg + (size_t)b*NPIX*64;
  const unsigned short* khp = khg + (size_t)b*NPIX*64;
  const unsigned short* klp = klg + (size_t)b*NPIX*64;
  const unsigned short* vhp = vhg + (size_t)b*CHN*NPIX;
  const unsigned short* vlp = vlg + (size_t)b*CHN*NPIX;

  short8 qh0 = *(const short8*)(qhp + (size_t)n_g*64 + 8*g);
  short8 qh1 = *(const short8*)(qhp + (size_t)n_g*64 + 8*g + 32);
  short8 ql0 = *(const short8*)(qlp + (size_t)n_g*64 + 8*g);
  short8 ql1 = *(const short8*)(qlp + (size_t)n_g*64 + 8*g + 32);

  f32x4 zero4 = {0.f,0.f,0.f,0.f};
  f32x4 oacc[4];
  #pragma unroll
  for (int vf=0; vf<4; ++vf) oacc[vf] = zero4;
  float m_run = -1e30f, l_run = 0.f;

  int nmax_w = rt*32 + w*16 + 15;

  for (int ti=0; ti<nt; ++ti){
    int m0 = C0 + (ti<<6);
    __syncthreads();
    #pragma unroll
    for (int p=0; p<4; ++p){
      int slot = t + (p<<7);                  // 512 slots / 128 threads
      int row = slot >> 3, cc = slot & 7;
      int off = row*128 + ((cc ^ (row & 7)) << 4);
      *(ushort8*)(KH + off) = *(const ushort8*)(khp + (size_t)(m0+row)*64 + cc*8);
      *(ushort8*)(KL + off) = *(const ushort8*)(klp + (size_t)(m0+row)*64 + cc*8);
      *(ushort8*)(VH + off) = *(const ushort8*)(vhp + (size_t)row*NPIX + m0 + cc*8);
      *(ushort8*)(VL + off) = *(const ushort8*)(vlp + (size_t)row*NPIX + m0 + cc*8);
    }
    __syncthreads();

    if (m0 <= nmax_w){
      // ---- S^T = K . Q^T ----
      f32x4 sf[4];
      #pragma unroll
      for (int mf=0; mf<4; ++mf) sf[mf] = zero4;
      #pragma unroll
      for (int kc=0; kc<2; ++kc){
        short8 qfh = kc ? qh1 : qh0;
        short8 qfl = kc ? ql1 : ql0;
        int ch = ((g + 4*kc) ^ (r & 7)) << 4;
        #pragma unroll
        for (int mf=0; mf<4; ++mf){
          int ro = (16*mf + r)*128;
          short8 ah = *(const short8*)(KH + ro + ch);
          short8 al = *(const short8*)(KL + ro + ch);
          sf[mf] = __builtin_amdgcn_mfma_f32_16x16x32_bf16(ah, qfh, sf[mf], 0,0,0);
          sf[mf] = __builtin_amdgcn_mfma_f32_16x16x32_bf16(al, qfh, sf[mf], 0,0,0);
          sf[mf] = __builtin_amdgcn_mfma_f32_16x16x32_bf16(ah, qfl, sf[mf], 0,0,0);
        }
      }
      // ---- online softmax: lane owns row n_g (scale pre-folded into q) ----
      float pv[16];
      float mx = -1e30f;
      #pragma unroll
      for (int mf=0; mf<4; ++mf){
        #pragma unroll
        for (int q2=0; q2<4; ++q2){
          int mg = m0 + 16*mf + 4*g + q2;
          float s = sf[mf][q2];
          s = (mg <= n_g) ? s : -1e30f;
          pv[mf*4+q2] = s;
          mx = fmaxf(mx, s);
        }
      }
      mx = fmaxf(mx, __shfl_xor(mx, 16));
      mx = fmaxf(mx, __shfl_xor(mx, 32));
      float m_new = fmaxf(m_run, mx);
      float alpha = __expf(m_run - m_new);
      float ps = 0.f;
      #pragma unroll
      for (int i=0; i<16; ++i){ pv[i] = __expf(pv[i] - m_new); ps += pv[i]; }
      ps += __shfl_xor(ps, 16);
      ps += __shfl_xor(ps, 32);
      l_run = l_run*alpha + ps;
      m_run = m_new;

      // ---- pack P hi/lo -> per-wave LDS tiles (same-wave, in-order DS) ----
      #pragma unroll
      for (int mf=0; mf<4; ++mf){
        unsigned short h_[4], l_[4];
        #pragma unroll
        for (int q2=0; q2<4; ++q2){
          float xv = pv[mf*4+q2];
          h_[q2] = f2bf(xv);
          l_[q2] = f2bf(xv - bf2f(h_[q2]));
        }
        int addr = r*128 + ((((g>>1) + 2*mf) ^ (r & 7)) << 4) + ((g&1)<<3);
        uint2 wh = make_uint2((unsigned)h_[0] | ((unsigned)h_[1]<<16),
                              (unsigned)h_[2] | ((unsigned)h_[3]<<16));
        uint2 wl = make_uint2((unsigned)l_[0] | ((unsigned)l_[1]<<16),
                              (unsigned)l_[2] | ((unsigned)l_[3]<<16));
        *(uint2*)(PH[w] + addr) = wh;
        *(uint2*)(PL[w] + addr) = wl;
      }
      #pragma unroll
      for (int vf=0; vf<4; ++vf) oacc[vf] *= alpha;

      // ---- out^T += V^T . P^T ----
      #pragma unroll
      for (int kc=0; kc<2; ++kc){
        int ch = ((g + 4*kc) ^ (r & 7)) << 4;
        short8 pfh = *(const short8*)(PH[w] + r*128 + ch);
        short8 pfl = *(const short8*)(PL[w] + r*128 + ch);
        #pragma unroll
        for (int vf=0; vf<4; ++vf){
          int ro = (16*vf + r)*128;
          short8 ah = *(const short8*)(VH + ro + ch);
          short8 al = *(const short8*)(VL + ro + ch);
          oacc[vf] = __builtin_amdgcn_mfma_f32_16x16x32_bf16(ah, pfh, oacc[vf], 0,0,0);
          oacc[vf] = __builtin_amdgcn_mfma_f32_16x16x32_bf16(al, pfh, oacc[vf], 0,0,0);
          oacc[vf] = __builtin_amdgcn_mfma_f32_16x16x32_bf16(ah, pfl, oacc[vf], 0,0,0);
        }
      }
    }
  }

  // ---- write partials: acc [32 n][64 vd], then m,l [32 n][2] ----
  float* pacc = part + (size_t)pidx * 2112;
  int nl = w*16 + r;
  #pragma unroll
  for (int vf=0; vf<4; ++vf)
    *(f32x4*)(pacc + nl*64 + 16*vf + 4*g) = oacc[vf];
  if (g == 0){
    pacc[2048 + nl*2]   = m_run;
    pacc[2048 + nl*2+1] = l_run;
  }
}

// ---------------- attention phase 2: combine chunk partials ----------------
__global__ __launch_bounds__(256) void attn_combine(const float* __restrict__ part,
                                                    float* __restrict__ out1){
  int bid = blockIdx.x;               // b*128 + rt
  int b = bid >> 7, rt = bid & 127;
  int k = rt >> 5;
  int nch = k + 1;
  int base = b*320 + 16*k*(k+1) + (rt - 32*k)*nch;

  int t = threadIdx.x;
  int nl = t & 31, vq = t >> 5;       // 32 rows x 8 vd-octets

  float M = -1e30f;
  #pragma unroll
  for (int c=0; c<4; ++c)
    if (c < nch) M = fmaxf(M, part[(size_t)(base+c)*2112 + 2048 + nl*2]);

  float L = 0.f;
  float val[8];
  #pragma unroll
  for (int jj=0; jj<8; ++jj) val[jj] = 0.f;
  #pragma unroll
  for (int c=0; c<4; ++c){
    if (c < nch){
      const float* pa = part + (size_t)(base+c)*2112;
      float wgt = __expf(pa[2048 + nl*2] - M);
      L += pa[2048 + nl*2 + 1] * wgt;
      #pragma unroll
      for (int jj=0; jj<8; ++jj) val[jj] += wgt * pa[nl*64 + vq*8 + jj];
    }
  }
  float invL = 1.f / L;
  #pragma unroll
  for (int jj=0; jj<8; ++jj)
    out1[((size_t)b*CHN + vq*8 + jj)*NPIX + rt*32 + nl] = val[jj]*invL;
}

// ---------------- final 1x1 conv: [100,64] x h — one output per thread -------
__global__ __launch_bounds__(256) void final_kernel(const float* __restrict__ h,
                                                    const float* __restrict__ ow,
                                                    const float* __restrict__ ob,
                                                    float* __restrict__ out){
  int idx = blockIdx.x*256 + threadIdx.x;     // 2*100*4096 = 819200
  int b  = idx / 409600;
  int r  = idx - b*409600;
  int oc = r >> 12;
  int n  = r & (NPIX-1);
  const float* hp = h + (size_t)b*CHN*NPIX + n;
  const float* wp = ow + oc*64;
  float acc = ob[oc];
  #pragma unroll
  for (int v=0; v<64; ++v) acc += wp[v]*hp[(size_t)v*NPIX];
  out[idx] = acc;
}

extern "C" void kernel_launch(void* const* d_in, const int* in_sizes, int n_in,
                              void* d_out, int out_size, void* d_ws, size_t ws_size,
                              hipStream_t stream){
  const float* x     = (const float*)d_in[0];
  const float* convw = (const float*)d_in[1];
  const float* convb = (const float*)d_in[2];
  const float* bn0g  = (const float*)d_in[3];
  const float* bn0b  = (const float*)d_in[4];
  const float* qw    = (const float*)d_in[5];
  const float* qbias = (const float*)d_in[6];
  const float* fkw   = (const float*)d_in[7];
  const float* fkb   = (const float*)d_in[8];
  const float* ckw   = (const float*)d_in[9];
  const float* ckb   = (const float*)d_in[10];
  const float* fvw   = (const float*)d_in[11];
  const float* fvb   = (const float*)d_in[12];
  const float* cvw   = (const float*)d_in[13];
  const float* cvb   = (const float*)d_in[14];
  const float* bng   = (const float*)d_in[15];
  const float* bnb   = (const float*)d_in[16];
  const float* ow    = (const float*)d_in[17];
  const float* ob    = (const float*)d_in[18];

  const size_t TEN = (size_t)2*CHN*NPIX;   // 524288 elements
  const size_t BFU = TEN/2;                // float-units per bf16 tensor
  float* ws   = (float*)d_ws;
  float* pos  = ws;                 // 131072
  float* h    = pos + 32*NPIX;
  float* k0   = h  + TEN;
  float* k1   = k0 + TEN;
  float* v0   = k1 + TEN;
  float* v1   = v0 + TEN;
  float* o1   = v1 + TEN;
  float* stats = o1 + TEN;          // 128
  float* wt   = stats + 128;        // 376832
  float* bfb  = wt + 376832;
  unsigned short* qh  = (unsigned short*)(bfb);
  unsigned short* ql  = (unsigned short*)(bfb + BFU);
  unsigned short* kh0 = (unsigned short*)(bfb + 2*BFU);
  unsigned short* kh1 = (unsigned short*)(bfb + 3*BFU);
  unsigned short* kl0 = (unsigned short*)(bfb + 4*BFU);
  unsigned short* kl1 = (unsigned short*)(bfb + 5*BFU);
  unsigned short* vh0 = (unsigned short*)(bfb + 6*BFU);
  unsigned short* vh1 = (unsigned short*)(bfb + 7*BFU);
  unsigned short* vl0 = (unsigned short*)(bfb + 8*BFU);
  unsigned short* vl1 = (unsigned short*)(bfb + 9*BFU);
  float* part = bfb + 10*BFU;       // 640 * 2112 floats

  hipMemsetAsync(k0, 0, TEN*sizeof(float), stream);
  hipMemsetAsync(v0, 0, TEN*sizeof(float), stream);
  hipMemsetAsync(kh0, 0, TEN*2, stream);
  hipMemsetAsync(kl0, 0, TEN*2, stream);
  hipMemsetAsync(vh0, 0, TEN*2, stream);
  hipMemsetAsync(vl0, 0, TEN*2, stream);

  pos_kernel<<<512,256,0,stream>>>(pos);
  wtr_kernel<<<1472,256,0,stream>>>(qw, fkw, ckw, fvw, cvw, wt);
  conv_in_kernel<<<128,256,0,stream>>>(x, convw, convb, o1);
  bn_stats_kernel<<<64,1024,0,stream>>>(o1, stats);
  bn_apply_kernel<<<512,256,0,stream>>>(o1, stats, bn0g, bn0b, h);

  float* kfp[2] = {k0,k1};
  float* vfp[2] = {v0,v1};
  unsigned short* khb[2] = {kh0,kh1};
  unsigned short* klb[2] = {kl0,kl1};
  unsigned short* vhb[2] = {vh0,vh1};
  unsigned short* vlb[2] = {vl0,vl1};
  for (int l=0; l<8; ++l){
    float* kold = kfp[l&1]; float* knew = kfp[(l+1)&1];
    float* vold = vfp[l&1]; float* vnew = vfp[(l+1)&1];
    cv1_kernel<<<512,256,0,stream>>>(h, pos, kold, vold,
        wt + l*6144,
        wt + 49152 + l*10240,
        wt + 49152 + 81920 + l*10240,
        wt + 49152 + 2*81920 + l*10240,
        wt + 49152 + 3*81920 + l*10240,
        qbias + l*64, fkb + l*64, ckb + l*64, fvb + l*64, cvb + l*64,
        qh, ql,
        knew, khb[(l+1)&1], klb[(l+1)&1],
        vnew, vhb[(l+1)&1], vlb[(l+1)&1]);
    attn_mfma<<<640,128,0,stream>>>(qh, ql, khb[l&1], klb[l&1], vhb[l&1], vlb[l&1], part);
    attn_combine<<<256,256,0,stream>>>(part, o1);
    bn_stats_kernel<<<64,1024,0,stream>>>(o1, stats);
    bn_apply_kernel<<<512,256,0,stream>>>(o1, stats, bng + l*64, bnb + l*64, h);
  }
  final_kernel<<<3200,256,0,stream>>>(h, ow, ob, (float*)d_out);
}

// Round 6
// 823.047 us; speedup vs baseline: 3.1577x; 1.0560x over previous
//
#include <hip/hip_runtime.h>

#define NPIX 4096
#define CHN  64

typedef __attribute__((ext_vector_type(8))) short short8;
typedef __attribute__((ext_vector_type(8))) unsigned short ushort8;
typedef __attribute__((ext_vector_type(4))) unsigned short ushort4v;
typedef __attribute__((ext_vector_type(4))) float f32x4;

__device__ __forceinline__ float lrelu_(float x){ return x >= 0.f ? x : 0.01f*x; }

__device__ __forceinline__ unsigned short f2bf(float x){
  union { float f; unsigned u; } v; v.f = x;
  unsigned r = v.u + 0x7FFF + ((v.u >> 16) & 1);
  return (unsigned short)(r >> 16);
}
__device__ __forceinline__ float bf2f(unsigned short h){
  union { unsigned u; float f; } v; v.u = ((unsigned)h) << 16;
  return v.f;
}

// ---------------- positional embedding table [32][4096] ----------------
__global__ void pos_kernel(float* __restrict__ pos){
  int idx = blockIdx.x*256 + threadIdx.x;       // 32*4096 = 131072
  int c = idx >> 12;
  int n = idx & (NPIX-1);
  int bcoord = (c < 16) ? (n >> 6) : (n & 63);
  int a = (c < 16) ? c : (c - 16);
  int flat = a*64 + bcoord;                     // index into pe flat [64*16]
  int p = flat >> 4;
  int j = flat & 15;
  float val = 0.f;
  if (p != 0){
    float ex = (float)(j & ~1) * (1.f/16.f);
    float w = powf(10000.f, -ex);
    float ang = (float)p * w;
    val = (j & 1) ? cosf(ang) : sinf(ang);
  }
  pos[idx] = val;
}

// ---------------- weight transpose ----------------
// wt: q 8*96*64 (49152) | fk/ck/fv/cv 8*160*64 (81920 each) | convw [tap75][o64] (4800)
__global__ void wtr_kernel(const float* __restrict__ qw, const float* __restrict__ fkw,
                           const float* __restrict__ ckw, const float* __restrict__ fvw,
                           const float* __restrict__ cvw, const float* __restrict__ convw,
                           float* __restrict__ wt){
  int idx = blockIdx.x*256 + threadIdx.x;
  if (idx >= 381632) return;
  if (idx < 49152){
    int l = idx / 6144, r = idx % 6144, i = r >> 6, o = r & 63;
    wt[idx] = qw[(l*64 + o)*96 + i];
  } else if (idx < 376832){
    int e = idx - 49152;
    int mat = e / 81920, r = e % 81920;
    int l = r / 10240, rr = r % 10240, i = rr >> 6, o = rr & 63;
    const float* src = (mat==0) ? fkw : (mat==1) ? ckw : (mat==2) ? fvw : cvw;
    wt[idx] = src[(l*64 + o)*160 + i];
  } else {
    int e = idx - 376832;          // [tap][o], tap = ci*25 + (ky*5+kx)
    int o = e & 63, tap = e >> 6;
    int ci = tap / 25, r = tap % 25;
    wt[idx] = convw[(o*3 + ci)*25 + r];
  }
}

// ---------------- masked causal 5x5 conv (input layer) ----------------
// block 256 = 64 oc x 4 px; grid 2048 = b*1024 + 4px-tile. Transposed weights.
__global__ __launch_bounds__(256) void conv_in_kernel(const float* __restrict__ x,
                                                      const float* __restrict__ cwt,
                                                      const float* __restrict__ cb,
                                                      float* __restrict__ out){
  int t = threadIdx.x;
  int o = t & 63;
  int sub = t >> 6;
  int bid = blockIdx.x;
  int b = bid >> 10;
  int n = ((bid & 1023) << 2) + sub;
  int y = n >> 6, xx = n & 63;
  float acc = cb[o];
  #pragma unroll
  for (int ci=0; ci<3; ++ci){
    const float* xp = x + ((b*3+ci)<<12);
    #pragma unroll
    for (int ky=0; ky<3; ++ky){
      int yy = y + ky - 2;
      if (yy < 0) continue;
      int nk = (ky==2) ? 2 : 5;
      #pragma unroll
      for (int kx=0; kx<5; ++kx){
        if (kx >= nk) break;
        int xc = xx + kx - 2;
        if (xc < 0 || xc > 63) continue;
        acc += xp[(yy<<6) + xc] * cwt[(ci*25 + ky*5 + kx)*64 + o];
      }
    }
  }
  out[(b*CHN+o)*NPIX + n] = acc;
}

// ---------------- batch-norm stats (biased var) per channel — conv path only --
__global__ __launch_bounds__(1024) void bn_stats_kernel(const float* __restrict__ xin,
                                                        float* __restrict__ stats){
  int c = blockIdx.x;
  int t = threadIdx.x;
  float s = 0.f, ss = 0.f;
  #pragma unroll
  for (int it=0; it<8; ++it){
    int idx = t + it*1024;
    float v = xin[(((idx>>12))*CHN + c)*NPIX + (idx & (NPIX-1))];
    s += v; ss += v*v;
  }
  #pragma unroll
  for (int o=1; o<64; o<<=1){ s += __shfl_xor(s,o); ss += __shfl_xor(ss,o); }
  __shared__ float ps[16], pq[16];
  if ((t & 63) == 0){ ps[t>>6] = s; pq[t>>6] = ss; }
  __syncthreads();
  if (t == 0){
    float S=0.f, Q=0.f;
    #pragma unroll
    for (int i=0;i<16;++i){ S += ps[i]; Q += pq[i]; }
    float mu = S*(1.f/8192.f);
    float var = Q*(1.f/8192.f) - mu*mu;
    var = fmaxf(var, 0.f);
    stats[c*2]   = mu;
    stats[c*2+1] = rsqrtf(var + 1e-5f);
  }
}

// ---------------- BN apply + LeakyReLU (conv path, from stats[]) ----------------
__global__ void bn_apply_kernel(const float* __restrict__ xin, const float* __restrict__ stats,
                                const float* __restrict__ g, const float* __restrict__ bb,
                                float* __restrict__ hout){
  int idx = blockIdx.x*256 + threadIdx.x;
  int e = idx << 2;
  int c = (e >> 12) & 63;
  float mu = stats[c*2], rstd = stats[c*2+1];
  float gain = g[c]*rstd;
  float beta = bb[c] - gain*mu;
  float4 v = *(const float4*)(xin + e);
  float4 r;
  r.x = lrelu_(gain*v.x + beta);
  r.y = lrelu_(gain*v.y + beta);
  r.z = lrelu_(gain*v.z + beta);
  r.w = lrelu_(gain*v.w + beta);
  *(float4*)(hout + e) = r;
}

// ---------------- BN apply + LeakyReLU from per-seg partials (layer path) -------
// grid 512: block covers 1024 consecutive floats of one (b,c) slab. psum/psq [c][256].
__global__ __launch_bounds__(256) void bn_apply2_kernel(const float* __restrict__ xin,
                                                        const float* __restrict__ psum,
                                                        const float* __restrict__ psq,
                                                        const float* __restrict__ g,
                                                        const float* __restrict__ bb,
                                                        float* __restrict__ hout){
  int bid = blockIdx.x;
  int ebase = bid << 10;
  int c = (ebase >> 12) & 63;
  int t = threadIdx.x;
  float s = psum[c*256 + t];
  float q = psq[c*256 + t];
  #pragma unroll
  for (int o=1; o<64; o<<=1){ s += __shfl_xor(s,o); q += __shfl_xor(q,o); }
  __shared__ float as[4], aq[4];
  if ((t & 63) == 0){ as[t>>6] = s; aq[t>>6] = q; }
  __syncthreads();
  float S = as[0]+as[1]+as[2]+as[3];
  float Q = aq[0]+aq[1]+aq[2]+aq[3];
  float mu = S*(1.f/8192.f);
  float var = fmaxf(Q*(1.f/8192.f) - mu*mu, 0.f);
  float rstd = rsqrtf(var + 1e-5f);
  float gain = g[c]*rstd;
  float beta = bb[c] - gain*mu;
  float4 v = *(const float4*)(xin + ebase + t*4);
  float4 r;
  r.x = lrelu_(gain*v.x + beta);
  r.y = lrelu_(gain*v.y + beta);
  r.z = lrelu_(gain*v.z + beta);
  r.w = lrelu_(gain*v.w + beta);
  *(float4*)(hout + ebase + t*4) = r;
}

// ---------------- five 1x1 convs -> q(hi/lo), k_new(fp32 + hi/lo), v_new(fp32 + hi/lo^T)
// grid 512 = b*256 + tile(16 n); block 256 = 4 waves x 4 px; lane = out-channel o
__global__ __launch_bounds__(256) void cv1_kernel(
    const float* __restrict__ hbuf, const float* __restrict__ pos,
    const float* __restrict__ kold, const float* __restrict__ vold,
    const float* __restrict__ qwt,
    const float* __restrict__ fkwt, const float* __restrict__ ckwt,
    const float* __restrict__ fvwt, const float* __restrict__ cvwt,
    const float* __restrict__ qbi,  const float* __restrict__ fkb,
    const float* __restrict__ ckb,  const float* __restrict__ fvb,
    const float* __restrict__ cvb,
    unsigned short* __restrict__ qh, unsigned short* __restrict__ ql,
    float* __restrict__ knew, unsigned short* __restrict__ khn, unsigned short* __restrict__ kln,
    float* __restrict__ vnew, unsigned short* __restrict__ vhTn, unsigned short* __restrict__ vlTn)
{
  int t = threadIdx.x;
  int o  = t & 63;
  int wv = t >> 6;                      // 0..3
  int b    = blockIdx.x >> 8;
  int tile = blockIdx.x & 255;
  int n0 = tile*16 + wv*4;

  const float* hb = hbuf + b*CHN*NPIX + n0;
  const float* kb = kold + b*CHN*NPIX + n0;
  const float* vb = vold + b*CHN*NPIX + n0;
  const float* pb = pos + n0;

  auto load4 = [&](const float* p, float* dst){
    float4 a = *(const float4*)p;
    dst[0]=a.x; dst[1]=a.y; dst[2]=a.z; dst[3]=a.w;
  };

  float x[4];
  long obase = (long)(b*CHN+o)*NPIX + n0;
  size_t nbase = ((size_t)b*NPIX + n0)*64 + o;   // [b][n][64] bf16 layouts

  // ---- q (96 inputs: h, pos); 1/8 attention scale folded in ----
  {
    float aq[4];
    float bias = qbi[o];
    #pragma unroll
    for (int j=0;j<4;++j) aq[j]=bias;
    #pragma unroll 4
    for (int i=0;i<64;++i){
      load4(hb + i*NPIX, x);
      float w = qwt[i*64 + o];
      #pragma unroll
      for (int j=0;j<4;++j) aq[j] += w*x[j];
    }
    #pragma unroll 4
    for (int i=0;i<32;++i){
      load4(pb + i*NPIX, x);
      float w = qwt[(64+i)*64 + o];
      #pragma unroll
      for (int j=0;j<4;++j) aq[j] += w*x[j];
    }
    #pragma unroll
    for (int j=0;j<4;++j){
      float v = lrelu_(aq[j]) * 0.125f;
      unsigned short hb16 = f2bf(v);
      qh[nbase + (size_t)j*64] = hb16;
      ql[nbase + (size_t)j*64] = f2bf(v - bf2f(hb16));
    }
  }

  // ---- fk/ck -> k_new ----
  {
    float af[4], ac[4];
    float bf = fkb[o], bc = ckb[o];
    #pragma unroll
    for (int j=0;j<4;++j){ af[j]=bf; ac[j]=bc; }
    #pragma unroll 4
    for (int i=0;i<64;++i){
      load4(hb + i*NPIX, x);
      float wf = fkwt[i*64+o], wc = ckwt[i*64+o];
      #pragma unroll
      for (int j=0;j<4;++j){ af[j] += wf*x[j]; ac[j] += wc*x[j]; }
    }
    #pragma unroll 4
    for (int i=0;i<32;++i){
      load4(pb + i*NPIX, x);
      float wf = fkwt[(64+i)*64+o], wc = ckwt[(64+i)*64+o];
      #pragma unroll
      for (int j=0;j<4;++j){ af[j] += wf*x[j]; ac[j] += wc*x[j]; }
    }
    #pragma unroll 4
    for (int i=0;i<64;++i){
      load4(kb + i*NPIX, x);
      float wf = fkwt[(96+i)*64+o], wc = ckwt[(96+i)*64+o];
      #pragma unroll
      for (int j=0;j<4;++j){ af[j] += wf*x[j]; ac[j] += wc*x[j]; }
    }
    float kv[4];
    load4(kb + o*NPIX, kv);
    #pragma unroll
    for (int j=0;j<4;++j){
      float fk = 1.f/(1.f+__expf(-af[j]));
      float kn = fk*kv[j] + lrelu_(ac[j]);
      knew[obase+j] = kn;
      unsigned short hb16 = f2bf(kn);
      khn[nbase + (size_t)j*64] = hb16;
      kln[nbase + (size_t)j*64] = f2bf(kn - bf2f(hb16));
    }
  }

  // ---- fv/cv -> v_new ----
  {
    float af[4], ac[4];
    float bf = fvb[o], bc = cvb[o];
    #pragma unroll
    for (int j=0;j<4;++j){ af[j]=bf; ac[j]=bc; }
    #pragma unroll 4
    for (int i=0;i<64;++i){
      load4(hb + i*NPIX, x);
      float wf = fvwt[i*64+o], wc = cvwt[i*64+o];
      #pragma unroll
      for (int j=0;j<4;++j){ af[j] += wf*x[j]; ac[j] += wc*x[j]; }
    }
    #pragma unroll 4
    for (int i=0;i<32;++i){
      load4(pb + i*NPIX, x);
      float wf = fvwt[(64+i)*64+o], wc = cvwt[(64+i)*64+o];
      #pragma unroll
      for (int j=0;j<4;++j){ af[j] += wf*x[j]; ac[j] += wc*x[j]; }
    }
    #pragma unroll 4
    for (int i=0;i<64;++i){
      load4(vb + i*NPIX, x);
      float wf = fvwt[(96+i)*64+o], wc = cvwt[(96+i)*64+o];
      #pragma unroll
      for (int j=0;j<4;++j){ af[j] += wf*x[j]; ac[j] += wc*x[j]; }
    }
    float vv[4];
    load4(vb + o*NPIX, vv);
    ushort4v vph, vpl;
    #pragma unroll
    for (int j=0;j<4;++j){
      float fv = 1.f/(1.f+__expf(-af[j]));
      float vn = fv*vv[j] + lrelu_(ac[j]);
      vnew[obase+j] = vn;
      unsigned short hb16 = f2bf(vn);
      vph[j] = hb16;
      vpl[j] = f2bf(vn - bf2f(hb16));
    }
    *(ushort4v*)(vhTn + ((size_t)(b*CHN+o))*NPIX + n0) = vph;   // [vd][n]
    *(ushort4v*)(vlTn + ((size_t)(b*CHN+o))*NPIX + n0) = vpl;
  }
}

// ---------------- MFMA flash attention, phase 1 (bf16 hi/lo split, fp32-accurate) ----
// grid 640: b(2) x band decomposition (rt 0..127 [32 rows], chunks of 1024 cols).
// block 128 = 2 waves x 16 q-rows. Swapped MFMA: S^T = K.Q^T, out^T = V^T.P^T.
// Async-STAGE split: next tile's global loads issued before compute (T14).
__global__ __launch_bounds__(128) void attn_mfma(
    const unsigned short* __restrict__ qhg, const unsigned short* __restrict__ qlg,
    const unsigned short* __restrict__ khg, const unsigned short* __restrict__ klg,
    const unsigned short* __restrict__ vhg, const unsigned short* __restrict__ vlg,
    float* __restrict__ part)
{
  int bid = 639 - (int)blockIdx.x;           // longest bands dispatched first
  int b = 0, id = bid;
  if (id >= 320){ b = 1; id -= 320; }
  int pidx = bid;
  int rem = id, k = 0;
  while (rem >= 32*(k+1)){ rem -= 32*(k+1); ++k; }
  int rt    = 32*k + rem/(k+1);
  int chunk = rem - (rem/(k+1))*(k+1);

  int C0  = chunk << 10;                      // 1024*chunk
  int end = min(C0 + 1024, rt*32 + 32);
  int nt  = (end - C0 + 63) >> 6;

  int t = threadIdx.x;
  int w = t >> 6;
  int l = t & 63;
  int r = l & 15;
  int g = l >> 4;
  int n_g = rt*32 + w*16 + r;                 // this lane's q-row

  __shared__ __align__(16) char KH[8192], KL[8192];  // [64 m][64 d] bf16, chunk-XOR swizzle
  __shared__ __align__(16) char VH[8192], VL[8192];  // [64 vd][64 m] bf16, swizzled
  __shared__ __align__(16) char PH[2][2048], PL[2][2048]; // per-wave [16 n][64 m]

  const unsigned short* qhp = qhg + (size_t)b*NPIX*64;
  const unsigned short* qlp = qlg + (size_t)b*NPIX*64;
  const unsigned short* khp = khg + (size_t)b*NPIX*64;
  const unsigned short* klp = klg + (size_t)b*NPIX*64;
  const unsigned short* vhp = vhg + (size_t)b*CHN*NPIX;
  const unsigned short* vlp = vlg + (size_t)b*CHN*NPIX;

  short8 qh0 = *(const short8*)(qhp + (size_t)n_g*64 + 8*g);
  short8 qh1 = *(const short8*)(qhp + (size_t)n_g*64 + 8*g + 32);
  short8 ql0 = *(const short8*)(qlp + (size_t)n_g*64 + 8*g);
  short8 ql1 = *(const short8*)(qlp + (size_t)n_g*64 + 8*g + 32);

  // per-thread staging slots (computed once)
  int srow[4], scc8[4], soff[4];
  #pragma unroll
  for (int p=0; p<4; ++p){
    int slot = t + (p<<7);
    int row = slot >> 3, cc = slot & 7;
    srow[p] = row; scc8[p] = cc*8;
    soff[p] = row*128 + ((cc ^ (row & 7)) << 4);
  }

  ushort8 rkh[4], rkl[4], rvh[4], rvl[4];
  auto issue = [&](int m0){
    #pragma unroll
    for (int p=0; p<4; ++p){
      rkh[p] = *(const ushort8*)(khp + (size_t)(m0+srow[p])*64 + scc8[p]);
      rkl[p] = *(const ushort8*)(klp + (size_t)(m0+srow[p])*64 + scc8[p]);
      rvh[p] = *(const ushort8*)(vhp + (size_t)srow[p]*NPIX + m0 + scc8[p]);
      rvl[p] = *(const ushort8*)(vlp + (size_t)srow[p]*NPIX + m0 + scc8[p]);
    }
  };

  f32x4 zero4 = {0.f,0.f,0.f,0.f};
  f32x4 oacc[4];
  #pragma unroll
  for (int vf=0; vf<4; ++vf) oacc[vf] = zero4;
  float m_run = -1e30f, l_run = 0.f;

  int nmax_w = rt*32 + w*16 + 15;

  issue(C0);
  for (int ti=0; ti<nt; ++ti){
    int m0 = C0 + (ti<<6);
    __syncthreads();                 // previous tile's LDS reads complete
    #pragma unroll
    for (int p=0; p<4; ++p){
      *(ushort8*)(KH + soff[p]) = rkh[p];
      *(ushort8*)(KL + soff[p]) = rkl[p];
      *(ushort8*)(VH + soff[p]) = rvh[p];
      *(ushort8*)(VL + soff[p]) = rvl[p];
    }
    __syncthreads();                 // tile staged
    if (ti+1 < nt) issue(m0 + 64);   // next tile's loads fly under compute

    if (m0 <= nmax_w){
      // ---- S^T = K . Q^T ----
      f32x4 sf[4];
      #pragma unroll
      for (int mf=0; mf<4; ++mf) sf[mf] = zero4;
      #pragma unroll
      for (int kc=0; kc<2; ++kc){
        short8 qfh = kc ? qh1 : qh0;
        short8 qfl = kc ? ql1 : ql0;
        int ch = ((g + 4*kc) ^ (r & 7)) << 4;
        #pragma unroll
        for (int mf=0; mf<4; ++mf){
          int ro = (16*mf + r)*128;
          short8 ah = *(const short8*)(KH + ro + ch);
          short8 al = *(const short8*)(KL + ro + ch);
          sf[mf] = __builtin_amdgcn_mfma_f32_16x16x32_bf16(ah, qfh, sf[mf], 0,0,0);
          sf[mf] = __builtin_amdgcn_mfma_f32_16x16x32_bf16(al, qfh, sf[mf], 0,0,0);
          sf[mf] = __builtin_amdgcn_mfma_f32_16x16x32_bf16(ah, qfl, sf[mf], 0,0,0);
        }
      }
      // ---- online softmax: lane owns row n_g (scale pre-folded into q) ----
      float pv[16];
      float mx = -1e30f;
      #pragma unroll
      for (int mf=0; mf<4; ++mf){
        #pragma unroll
        for (int q2=0; q2<4; ++q2){
          int mg = m0 + 16*mf + 4*g + q2;
          float s = sf[mf][q2];
          s = (mg <= n_g) ? s : -1e30f;
          pv[mf*4+q2] = s;
          mx = fmaxf(mx, s);
        }
      }
      mx = fmaxf(mx, __shfl_xor(mx, 16));
      mx = fmaxf(mx, __shfl_xor(mx, 32));
      float m_new = fmaxf(m_run, mx);
      float alpha = __expf(m_run - m_new);
      float ps = 0.f;
      #pragma unroll
      for (int i=0; i<16; ++i){ pv[i] = __expf(pv[i] - m_new); ps += pv[i]; }
      ps += __shfl_xor(ps, 16);
      ps += __shfl_xor(ps, 32);
      l_run = l_run*alpha + ps;
      m_run = m_new;

      // ---- pack P hi/lo -> per-wave LDS tiles (same-wave, in-order DS) ----
      #pragma unroll
      for (int mf=0; mf<4; ++mf){
        unsigned short h_[4], l_[4];
        #pragma unroll
        for (int q2=0; q2<4; ++q2){
          float xv = pv[mf*4+q2];
          h_[q2] = f2bf(xv);
          l_[q2] = f2bf(xv - bf2f(h_[q2]));
        }
        int addr = r*128 + ((((g>>1) + 2*mf) ^ (r & 7)) << 4) + ((g&1)<<3);
        uint2 wh = make_uint2((unsigned)h_[0] | ((unsigned)h_[1]<<16),
                              (unsigned)h_[2] | ((unsigned)h_[3]<<16));
        uint2 wl = make_uint2((unsigned)l_[0] | ((unsigned)l_[1]<<16),
                              (unsigned)l_[2] | ((unsigned)l_[3]<<16));
        *(uint2*)(PH[w] + addr) = wh;
        *(uint2*)(PL[w] + addr) = wl;
      }
      #pragma unroll
      for (int vf=0; vf<4; ++vf) oacc[vf] *= alpha;

      // ---- out^T += V^T . P^T ----
      #pragma unroll
      for (int kc=0; kc<2; ++kc){
        int ch = ((g + 4*kc) ^ (r & 7)) << 4;
        short8 pfh = *(const short8*)(PH[w] + r*128 + ch);
        short8 pfl = *(const short8*)(PL[w] + r*128 + ch);
        #pragma unroll
        for (int vf=0; vf<4; ++vf){
          int ro = (16*vf + r)*128;
          short8 ah = *(const short8*)(VH + ro + ch);
          short8 al = *(const short8*)(VL + ro + ch);
          oacc[vf] = __builtin_amdgcn_mfma_f32_16x16x32_bf16(ah, pfh, oacc[vf], 0,0,0);
          oacc[vf] = __builtin_amdgcn_mfma_f32_16x16x32_bf16(al, pfh, oacc[vf], 0,0,0);
          oacc[vf] = __builtin_amdgcn_mfma_f32_16x16x32_bf16(ah, pfl, oacc[vf], 0,0,0);
        }
      }
    }
  }

  // ---- write partials: acc [32 n][64 vd], then m,l [32 n][2] ----
  float* pacc = part + (size_t)pidx * 2112;
  int nl = w*16 + r;
  #pragma unroll
  for (int vf=0; vf<4; ++vf)
    *(f32x4*)(pacc + nl*64 + 16*vf + 4*g) = oacc[vf];
  if (g == 0){
    pacc[2048 + nl*2]   = m_run;
    pacc[2048 + nl*2+1] = l_run;
  }
}

// ---------------- attention phase 2: combine partials + emit BN partial sums ----
__global__ __launch_bounds__(256) void attn_combine(const float* __restrict__ part,
                                                    float* __restrict__ out1,
                                                    float* __restrict__ psum,
                                                    float* __restrict__ psq){
  int bid = blockIdx.x;               // b*128 + rt
  int b = bid >> 7, rt = bid & 127;
  int k = rt >> 5;
  int nch = k + 1;
  int base = b*320 + 16*k*(k+1) + (rt - 32*k)*nch;

  int t = threadIdx.x;
  int nl = t & 31, vq = t >> 5;       // 32 rows x 8 vd-octets

  float M = -1e30f;
  #pragma unroll
  for (int c=0; c<4; ++c)
    if (c < nch) M = fmaxf(M, part[(size_t)(base+c)*2112 + 2048 + nl*2]);

  float L = 0.f;
  float val[8];
  #pragma unroll
  for (int jj=0; jj<8; ++jj) val[jj] = 0.f;
  #pragma unroll
  for (int c=0; c<4; ++c){
    if (c < nch){
      const float* pa = part + (size_t)(base+c)*2112;
      float wgt = __expf(pa[2048 + nl*2] - M);
      L += pa[2048 + nl*2 + 1] * wgt;
      #pragma unroll
      for (int jj=0; jj<8; ++jj) val[jj] += wgt * pa[nl*64 + vq*8 + jj];
    }
  }
  float invL = 1.f / L;
  float s[8], q[8];
  #pragma unroll
  for (int jj=0; jj<8; ++jj){
    float v = val[jj]*invL;
    out1[((size_t)b*CHN + vq*8 + jj)*NPIX + rt*32 + nl] = v;
    s[jj] = v; q[jj] = v*v;
  }
  // reduce over the 32 pixels (nl lanes) of this block slice
  #pragma unroll
  for (int o2=1; o2<32; o2<<=1){
    #pragma unroll
    for (int jj=0; jj<8; ++jj){
      s[jj] += __shfl_xor(s[jj], o2);
      q[jj] += __shfl_xor(q[jj], o2);
    }
  }
  if (nl == 0){
    #pragma unroll
    for (int jj=0; jj<8; ++jj){
      int c = vq*8 + jj;
      psum[c*256 + bid] = s[jj];
      psq [c*256 + bid] = q[jj];
    }
  }
}

// ---------------- final 1x1 conv: [100,64] x h — one output per thread -------
__global__ __launch_bounds__(256) void final_kernel(const float* __restrict__ h,
                                                    const float* __restrict__ ow,
                                                    const float* __restrict__ ob,
                                                    float* __restrict__ out){
  int idx = blockIdx.x*256 + threadIdx.x;     // 2*100*4096 = 819200
  int b  = idx / 409600;
  int r  = idx - b*409600;
  int oc = r >> 12;
  int n  = r & (NPIX-1);
  const float* hp = h + (size_t)b*CHN*NPIX + n;
  const float* wp = ow + oc*64;
  float acc = ob[oc];
  #pragma unroll
  for (int v=0; v<64; ++v) acc += wp[v]*hp[(size_t)v*NPIX];
  out[idx] = acc;
}

extern "C" void kernel_launch(void* const* d_in, const int* in_sizes, int n_in,
                              void* d_out, int out_size, void* d_ws, size_t ws_size,
                              hipStream_t stream){
  const float* x     = (const float*)d_in[0];
  const float* convw = (const float*)d_in[1];
  const float* convb = (const float*)d_in[2];
  const float* bn0g  = (const float*)d_in[3];
  const float* bn0b  = (const float*)d_in[4];
  const float* qw    = (const float*)d_in[5];
  const float* qbias = (const float*)d_in[6];
  const float* fkw   = (const float*)d_in[7];
  const float* fkb   = (const float*)d_in[8];
  const float* ckw   = (const float*)d_in[9];
  const float* ckb   = (const float*)d_in[10];
  const float* fvw   = (const float*)d_in[11];
  const float* fvb   = (const float*)d_in[12];
  const float* cvw   = (const float*)d_in[13];
  const float* cvb   = (const float*)d_in[14];
  const float* bng   = (const float*)d_in[15];
  const float* bnb   = (const float*)d_in[16];
  const float* ow    = (const float*)d_in[17];
  const float* ob    = (const float*)d_in[18];

  const size_t TEN = (size_t)2*CHN*NPIX;   // 524288 elements
  const size_t BFU = TEN/2;                // float-units per bf16 tensor
  float* ws   = (float*)d_ws;
  float* pos  = ws;                 // 131072
  float* h    = pos + 32*NPIX;
  float* k0   = h  + TEN;
  float* k1   = k0 + TEN;
  float* v0   = k1 + TEN;
  float* v1   = v0 + TEN;
  float* o1   = v1 + TEN;
  float* stats = o1 + TEN;          // 128
  float* psum = stats + 128;        // 64*256
  float* psq  = psum + 64*256;      // 64*256
  float* wt   = psq + 64*256;       // 381632
  float* bfb  = wt + 381632;
  unsigned short* qh  = (unsigned short*)(bfb);
  unsigned short* ql  = (unsigned short*)(bfb + BFU);
  unsigned short* kh0 = (unsigned short*)(bfb + 2*BFU);
  unsigned short* kh1 = (unsigned short*)(bfb + 3*BFU);
  unsigned short* kl0 = (unsigned short*)(bfb + 4*BFU);
  unsigned short* kl1 = (unsigned short*)(bfb + 5*BFU);
  unsigned short* vh0 = (unsigned short*)(bfb + 6*BFU);
  unsigned short* vh1 = (unsigned short*)(bfb + 7*BFU);
  unsigned short* vl0 = (unsigned short*)(bfb + 8*BFU);
  unsigned short* vl1 = (unsigned short*)(bfb + 9*BFU);
  float* part = bfb + 10*BFU;       // 640 * 2112 floats

  hipMemsetAsync(k0, 0, TEN*sizeof(float), stream);
  hipMemsetAsync(v0, 0, TEN*sizeof(float), stream);
  hipMemsetAsync(kh0, 0, TEN*2, stream);
  hipMemsetAsync(kl0, 0, TEN*2, stream);
  hipMemsetAsync(vh0, 0, TEN*2, stream);
  hipMemsetAsync(vl0, 0, TEN*2, stream);

  pos_kernel<<<512,256,0,stream>>>(pos);
  wtr_kernel<<<1491,256,0,stream>>>(qw, fkw, ckw, fvw, cvw, convw, wt);
  conv_in_kernel<<<2048,256,0,stream>>>(x, wt + 376832, convb, o1);
  bn_stats_kernel<<<64,1024,0,stream>>>(o1, stats);
  bn_apply_kernel<<<512,256,0,stream>>>(o1, stats, bn0g, bn0b, h);

  float* kfp[2] = {k0,k1};
  float* vfp[2] = {v0,v1};
  unsigned short* khb[2] = {kh0,kh1};
  unsigned short* klb[2] = {kl0,kl1};
  unsigned short* vhb[2] = {vh0,vh1};
  unsigned short* vlb[2] = {vl0,vl1};
  for (int l=0; l<8; ++l){
    float* kold = kfp[l&1]; float* knew = kfp[(l+1)&1];
    float* vold = vfp[l&1]; float* vnew = vfp[(l+1)&1];
    cv1_kernel<<<512,256,0,stream>>>(h, pos, kold, vold,
        wt + l*6144,
        wt + 49152 + l*10240,
        wt + 49152 + 81920 + l*10240,
        wt + 49152 + 2*81920 + l*10240,
        wt + 49152 + 3*81920 + l*10240,
        qbias + l*64, fkb + l*64, ckb + l*64, fvb + l*64, cvb + l*64,
        qh, ql,
        knew, khb[(l+1)&1], klb[(l+1)&1],
        vnew, vhb[(l+1)&1], vlb[(l+1)&1]);
    attn_mfma<<<640,128,0,stream>>>(qh, ql, khb[l&1], klb[l&1], vhb[l&1], vlb[l&1], part);
    attn_combine<<<256,256,0,stream>>>(part, o1, psum, psq);
    bn_apply2_kernel<<<512,256,0,stream>>>(o1, psum, psq, bng + l*64, bnb + l*64, h);
  }
  final_kernel<<<3200,256,0,stream>>>(h, ow, ob, (float*)d_out);
}